// Round 1
// 182.681 us; speedup vs baseline: 1.0130x; 1.0130x over previous
//
#include <hip/hip_runtime.h>
#include <hip/hip_bf16.h>

// Problem: B=2, T=2048, D=1024, H=16, HD=64.
// Runtime-detect fp32 vs bf16 inputs (inline, per-wave); canonicalize to bf16.
// convert_all -> qkv gemm (128x128 reg-prefetch; Q,K:[B,H,T,64] via LDS-
// transpose epilogue; V:[B,H,64,T]) -> split-S flash attention (32x32 MFMA,
// swapped QK^T, in-register softmax via cvt_pk_bf16 + permlane32_swap,
// fixed-shift softmax, K/V LDS double-buffer w/ 1 barrier/tile, MFMA ones-row
// l) -> merge -> out gemm (64x128).

#define TB 2
#define TT 2048
#define TD 1024
#define TH 16
#define TM (TB * TT) // 4096

#define NEG_BIG (-1e30f)
#define SCALE_LOG2 0.18033688f  // (1/sqrt(64)) * log2(e)
#define FSHIFT 16.0f            // fixed softmax shift (exact; cancels in O/l)
#define BF16_ONE ((short)0x3F80)

typedef __attribute__((ext_vector_type(8))) short short8;
typedef __attribute__((ext_vector_type(4))) float f32x4;
typedef __attribute__((ext_vector_type(16))) float f32x16;
typedef __attribute__((ext_vector_type(4))) unsigned short ushort4v;
typedef __attribute__((ext_vector_type(4))) unsigned int u32x4;

__device__ __forceinline__ short f2bf(float f) {
    __hip_bfloat16 h = __float2bfloat16(f);
    return __builtin_bit_cast(short, h);
}

__device__ __forceinline__ float bf2f(short u) {
    unsigned int x = ((unsigned int)(unsigned short)u) << 16;
    return __builtin_bit_cast(float, x);
}

__device__ __forceinline__ float fast_exp2(float x) {
#if __has_builtin(__builtin_amdgcn_exp2f)
    return __builtin_amdgcn_exp2f(x);
#else
    return exp2f(x);
#endif
}

__device__ __forceinline__ f32x16 zero16() {
    f32x16 v;
    #pragma unroll
    for (int i = 0; i < 16; ++i) v[i] = 0.f;
    return v;
}

// Inline dtype detect: sample even u16s of x; uniform per wave.
__device__ __forceinline__ int detect_bf16(const unsigned short* xq) {
    int lane = threadIdx.x & 63;
    unsigned short u = xq[lane * 2];
    int e = (u >> 7) & 0xFF;
    int sane = ((e >= 100 && e <= 145) || u == 0) ? 1 : 0;
    unsigned long long b = __ballot(sane);
    return (__popcll(b) >= 48) ? 1 : 0; // 1 = bf16, 0 = fp32
}

// ---------------------------------------------------------------------------
// One dispatch converts x + 4 weights; 8192 elems/block.
// ---------------------------------------------------------------------------
__global__ __launch_bounds__(256) void convert_all_kernel(
    const void* __restrict__ x,  const void* __restrict__ wq,
    const void* __restrict__ wk, const void* __restrict__ wv,
    const void* __restrict__ wo,
    short* __restrict__ xb, short* __restrict__ wqb, short* __restrict__ wkb,
    short* __restrict__ wvb, short* __restrict__ wob)
{
    const int f = detect_bf16((const unsigned short*)x);
    int bid = blockIdx.x;
    const void* src; short* dst; int base;
    if (bid < 512) { src = x; dst = xb; base = bid; }
    else {
        int w = (bid - 512) >> 7, lb = (bid - 512) & 127;
        src = (w == 0) ? wq : (w == 1) ? wk : (w == 2) ? wv : wo;
        dst = (w == 0) ? wqb : (w == 1) ? wkb : (w == 2) ? wvb : wob;
        base = lb;
    }
    int i0 = base * 8192 + (int)threadIdx.x * 8;
    #pragma unroll
    for (int r = 0; r < 4; ++r) {
        int i = i0 + r * 2048;
        if (f) {
            *(short8*)(dst + i) = *(const short8*)((const short*)src + i);
        } else {
            const float* s = (const float*)src + i;
            short8 o;
            #pragma unroll
            for (int j = 0; j < 8; ++j) o[j] = f2bf(s[j]);
            *(short8*)(dst + i) = o;
        }
    }
}

// ---------------------------------------------------------------------------
// GEMM core, register-prefetch pipeline. C[m,n] = sum_k A[m,k]*B[n,k].
// Tile: MROWS x 128, BK=64, K=1024. 4 waves (2x2). XOR chunk swizzle.
// ---------------------------------------------------------------------------
template<int MROWS>
__device__ __forceinline__ void gemm_core_regpf(
    const short* __restrict__ A, const short* __restrict__ B,
    short* SM, int mbase, int nbase, f32x4 (*acc)[4])
{
    constexpr int TA = MROWS / 32;
    short* As = SM;
    short* Bs = SM + MROWS * 64;

    const int tid = threadIdx.x;
    const int wave = tid >> 6, lane = tid & 63;
    const int wm = wave >> 1, wn = wave & 1;
    const int lr = lane & 15;
    const int srow = lane >> 3, jcl = lane & 7;

    #pragma unroll
    for (int a = 0; a < TA; ++a)
        #pragma unroll
        for (int b = 0; b < 4; ++b) acc[a][b] = (f32x4){0, 0, 0, 0};

    short8 an[TA], bn[4];
    #pragma unroll
    for (int t = 0; t < TA; ++t) {
        int w = wave * TA + t, r = w * 8 + srow, jc = jcl ^ (r & 7);
        an[t] = *(const short8*)&A[(size_t)(mbase + r) * TD + jc * 8];
    }
    #pragma unroll
    for (int t = 0; t < 4; ++t) {
        int w = wave * 4 + t, r = w * 8 + srow, jc = jcl ^ (r & 7);
        bn[t] = *(const short8*)&B[(size_t)(nbase + r) * TD + jc * 8];
    }
    #pragma unroll
    for (int t = 0; t < TA; ++t) *(short8*)&As[(wave * TA + t) * 512 + lane * 8] = an[t];
    #pragma unroll
    for (int t = 0; t < 4; ++t)  *(short8*)&Bs[(wave * 4 + t) * 512 + lane * 8] = bn[t];
    __syncthreads();

    for (int k0 = 0; k0 < TD; k0 += 64) {
        const bool more = (k0 + 64) < TD;
        if (more) {
            #pragma unroll
            for (int t = 0; t < TA; ++t) {
                int w = wave * TA + t, r = w * 8 + srow, jc = jcl ^ (r & 7);
                an[t] = *(const short8*)&A[(size_t)(mbase + r) * TD + k0 + 64 + jc * 8];
            }
            #pragma unroll
            for (int t = 0; t < 4; ++t) {
                int w = wave * 4 + t, r = w * 8 + srow, jc = jcl ^ (r & 7);
                bn[t] = *(const short8*)&B[(size_t)(nbase + r) * TD + k0 + 64 + jc * 8];
            }
        }
        #pragma unroll
        for (int kk = 0; kk < 64; kk += 32) {
            const int cc = (kk >> 3) + (lane >> 4);
            const int csw = (cc ^ (lr & 7)) << 3;
            short8 af[TA], bf[4];
            #pragma unroll
            for (int a = 0; a < TA; ++a)
                af[a] = *(const short8*)&As[(wm * (MROWS / 2) + a * 16 + lr) * 64 + csw];
            #pragma unroll
            for (int b = 0; b < 4; ++b)
                bf[b] = *(const short8*)&Bs[(wn * 64 + b * 16 + lr) * 64 + csw];
            #pragma unroll
            for (int a = 0; a < TA; ++a)
                #pragma unroll
                for (int b = 0; b < 4; ++b)
                    acc[a][b] = __builtin_amdgcn_mfma_f32_16x16x32_bf16(af[a], bf[b], acc[a][b], 0, 0, 0);
        }
        __syncthreads();
        if (more) {
            #pragma unroll
            for (int t = 0; t < TA; ++t) *(short8*)&As[(wave * TA + t) * 512 + lane * 8] = an[t];
            #pragma unroll
            for (int t = 0; t < 4; ++t)  *(short8*)&Bs[(wave * 4 + t) * 512 + lane * 8] = bn[t];
            __syncthreads();
        }
    }
}

// ---------------------------------------------------------------------------
// QKV projection; 128x128 tiles, grid (32, 8, 3).
// Q,K out [B,H,T,64] via LDS-transposed coalesced epilogue; V out [B,H,64,T].
// ---------------------------------------------------------------------------
__global__ __launch_bounds__(256, 3) void qkv_gemm_kernel(
    const short* __restrict__ x,
    const short* __restrict__ Wq, const short* __restrict__ Wk,
    const short* __restrict__ Wv,
    short* __restrict__ Qo, short* __restrict__ Ko, short* __restrict__ Vo)
{
    const short* W = (blockIdx.z == 0) ? Wq : (blockIdx.z == 1) ? Wk : Wv;
    short* Out = (blockIdx.z == 0) ? Qo : (blockIdx.z == 1) ? Ko : Vo;
    const bool transposeV = (blockIdx.z == 2);

    __shared__ __align__(16) short SM[128 * 64 * 2];

    const int mbase = blockIdx.x * 128, nbase = blockIdx.y * 128;
    f32x4 acc[4][4];
    gemm_core_regpf<128>(x, W, SM, mbase, nbase, acc);

    const int tid = threadIdx.x;
    const int wave = tid >> 6, lane = tid & 63;
    const int wm = wave >> 1, wn = wave & 1;
    const int lr = lane & 15;
    const int g4 = (lane >> 4) * 4;

    if (transposeV) {
        #pragma unroll
        for (int a = 0; a < 4; ++a) {
            #pragma unroll
            for (int b = 0; b < 4; ++b) {
                int m0 = mbase + wm * 64 + a * 16 + g4;
                int n = nbase + wn * 64 + b * 16 + lr;
                int bb = m0 >> 11, t0 = m0 & (TT - 1);
                int h = n >> 6, hd = n & 63;
                ushort4v pk;
                #pragma unroll
                for (int i = 0; i < 4; ++i) pk[i] = (unsigned short)f2bf(acc[a][b][i]);
                *(ushort4v*)&Out[((size_t)(bb * TH + h) * 64 + hd) * TT + t0] = pk;
            }
        }
    } else {
        short* Cs = SM;
        #pragma unroll
        for (int p = 0; p < 2; ++p) {
            __syncthreads();
            if (wn == p) {
                #pragma unroll
                for (int a = 0; a < 4; ++a)
                    #pragma unroll
                    for (int b = 0; b < 4; ++b)
                        #pragma unroll
                        for (int i = 0; i < 4; ++i) {
                            int ml = wm * 64 + a * 16 + g4 + i;
                            int nl = b * 16 + lr;
                            Cs[ml * 72 + nl] = f2bf(acc[a][b][i]);
                        }
            }
            __syncthreads();
            int tl = tid >> 1, hc = (tid & 1) * 32;
            int h = (nbase >> 6) + p;
            int m = mbase + tl;
            int bb = m >> 11, t = m & (TT - 1);
            size_t base = (((size_t)(bb * TH + h) * TT + t) << 6) + hc;
            #pragma unroll
            for (int q = 0; q < 4; ++q)
                *(short8*)&Out[base + q * 8] = *(short8*)&Cs[tl * 72 + hc + q * 8];
        }
    }
}

// ---------------------------------------------------------------------------
// Output projection; 64x128 tiles, grid (64, 8).
// ---------------------------------------------------------------------------
__global__ __launch_bounds__(256, 2) void out_gemm_kernel(
    const short* __restrict__ A, const short* __restrict__ W,
    void* __restrict__ C, const unsigned short* __restrict__ xq)
{
    const int f = detect_bf16(xq);

    __shared__ __align__(16) short SM[64 * 64 + 128 * 64];

    const int mbase = blockIdx.x * 64, nbase = blockIdx.y * 128;
    f32x4 acc[2][4];
    gemm_core_regpf<64>(A, W, SM, mbase, nbase, acc);

    const int tid = threadIdx.x;
    const int wave = tid >> 6, lane = tid & 63;
    const int wm = wave >> 1, wn = wave & 1;
    const int lr = lane & 15;
    const int g4 = (lane >> 4) * 4;

    #pragma unroll
    for (int a = 0; a < 2; ++a) {
        #pragma unroll
        for (int b = 0; b < 4; ++b) {
            #pragma unroll
            for (int i = 0; i < 4; ++i) {
                int m = mbase + wm * 32 + a * 16 + g4 + i;
                int n = nbase + wn * 64 + b * 16 + lr;
                if (f) ((short*)C)[(size_t)m * TD + n] = f2bf(acc[a][b][i]);
                else   ((float*)C)[(size_t)m * TD + n] = acc[a][b][i];
            }
        }
    }
}

// ---------------------------------------------------------------------------
// Split-S flash attention, 32x32 MFMA, swapped QK^T (S^T = K Q^T), softmax
// fully in registers, P->bf16 via v_cvt_pk_bf16_f32 + v_permlane32_swap_b32,
// l on the MFMA pipe via ones-A-frag. 128 q-rows/block (4 waves x 32 q-rows),
// K/V LDS double-buffer, ONE barrier per 64-k tile. grid (32 bh, 32 work).
// work y: qt = 15 - (y>>1) (heaviest first), half = y&1; half0 = tiles
// [0, qt+1), half1 = [qt+1, 2qt+2) -- both always non-empty.
// Epilogue: O^T -> LDS (f32) -> transposed coalesced bf16 Opart [q][hd].
// ---------------------------------------------------------------------------
__global__ __launch_bounds__(256, 3) void attn_split_kernel(
    const short* __restrict__ Q, const short* __restrict__ K,
    const short* __restrict__ V, short* __restrict__ Opart,
    float* __restrict__ lbuf)
{
    const int bh = blockIdx.x;
    const int y = blockIdx.y;
    const int qt = 15 - (y >> 1);
    const int half = y & 1;
    const int nt0 = qt + 1;
    const int tb = half ? nt0 : 0;
    const int te = half ? (2 * qt + 2) : nt0;

    const int qbase = qt * 128;
    const short* Qp = Q + (size_t)bh * TT * 64;
    const short* Kp = K + (size_t)bh * TT * 64;
    const short* Vp = V + (size_t)bh * 64 * TT;   // V^T: [64][TT]

    __shared__ __align__(16) short SMEM[18432];   // Ks[2][64][72] | Vt[2][64][72]
    short (*Ks)[64][72] = (short (*)[64][72])(SMEM);
    short (*Vt)[64][72] = (short (*)[64][72])(SMEM + 9216);

    const int tid = threadIdx.x;
    const int wave = tid >> 6, lane = tid & 63;
    const int l31 = lane & 31, g = lane >> 5;

    const size_t pslot = (size_t)((half * 32 + bh) * 16 + qt);
    float* lrow = lbuf + pslot * 128;
    short* Ob = Opart + pslot * 8192;

    // staging coords: each thread stages 2 K rows + 2 V rows, 16B each
    const int r0 = tid >> 3, c0 = (tid & 7) * 8;
    const int r1 = r0 + 32;

    // Q fragments (B-operand): lane holds q-row qrow, 64 hd in 4 chunks
    const int qrow0 = qbase + wave * 32;      // wave's min q (uniform)
    const int qrow = qrow0 + l31;             // this lane's q row
    short8 qf[4];
    #pragma unroll
    for (int c = 0; c < 4; ++c)
        qf[c] = *(const short8*)&Qp[(size_t)qrow * 64 + c * 16 + g * 8];

    short8 ones8;
    #pragma unroll
    for (int i = 0; i < 8; ++i) ones8[i] = BF16_ONE;

    f32x16 Oa[2];                // O^T accum: [hd-tile][ (hd-row, q) frag ]
    Oa[0] = zero16(); Oa[1] = zero16();
    f32x16 La = zero16();        // l (all 32 rows identical = l[q])

    // prologue: stage first tile into buf 0
    {
        const int kb = tb * 64;
        *(short8*)&Ks[0][r0][c0] = *(const short8*)&Kp[(size_t)(kb + r0) * 64 + c0];
        *(short8*)&Ks[0][r1][c0] = *(const short8*)&Kp[(size_t)(kb + r1) * 64 + c0];
        *(short8*)&Vt[0][r0][c0] = *(const short8*)&Vp[(size_t)r0 * TT + kb + c0];
        *(short8*)&Vt[0][r1][c0] = *(const short8*)&Vp[(size_t)r1 * TT + kb + c0];
    }
    __syncthreads();

    int buf = 0;
    for (int it = tb; it < te; ++it) {
        const int kt = it * 64;
        const bool more = (it + 1) < te;
        short8 ka, kb2, va, vb;
        if (more) {
            const int kn = kt + 64;
            ka  = *(const short8*)&Kp[(size_t)(kn + r0) * 64 + c0];
            kb2 = *(const short8*)&Kp[(size_t)(kn + r1) * 64 + c0];
            va  = *(const short8*)&Vp[(size_t)r0 * TT + kn + c0];
            vb  = *(const short8*)&Vp[(size_t)r1 * TT + kn + c0];
        }

        #pragma unroll
        for (int t = 0; t < 2; ++t) {
            const int kb32 = kt + t * 32;
            if (kb32 > qrow0 + 31) continue;   // fully masked (wave-uniform)

            // S^T subtile = K(32 k-rows) . Q^T, accumulate over hd
            f32x16 S = zero16();
            #pragma unroll
            for (int c = 0; c < 4; ++c) {
                short8 kf = *(const short8*)&Ks[buf][t * 32 + l31][c * 16 + g * 8];
                S = __builtin_amdgcn_mfma_f32_32x32x16_bf16(kf, qf[c], S, 0, 0, 0);
            }

            // P = 2^(S*scale - 16); causal mask -> 0 (exact fixed-shift)
            float p[16];
            const bool partm = (kb32 + 31) > qrow0;
            if (partm) {
                #pragma unroll
                for (int r = 0; r < 16; ++r) {
                    int kglob = kb32 + (r & 3) + ((r >> 2) << 3) + 4 * g;
                    float arg = S[r] * SCALE_LOG2 - FSHIFT;
                    p[r] = fast_exp2(kglob > qrow ? NEG_BIG : arg);
                }
            } else {
                #pragma unroll
                for (int r = 0; r < 16; ++r)
                    p[r] = fast_exp2(S[r] * SCALE_LOG2 - FSHIFT);
            }

            // pack to bf16 B-fragments in-register (T12):
            // word(c2,j): lane-half g holds k-pair {16c2+8g+2j, +1}
            unsigned int w[8];
            #pragma unroll
            for (int j = 0; j < 2; ++j) {
                unsigned int a, b;
                asm("v_cvt_pk_bf16_f32 %0, %1, %2" : "=v"(a) : "v"(p[2 * j]), "v"(p[2 * j + 1]));
                asm("v_cvt_pk_bf16_f32 %0, %1, %2" : "=v"(b) : "v"(p[2 * j + 4]), "v"(p[2 * j + 5]));
                asm("v_permlane32_swap_b32 %0, %1" : "+v"(a), "+v"(b));
                w[j] = a; w[j + 2] = b;
                unsigned int a2, b2;
                asm("v_cvt_pk_bf16_f32 %0, %1, %2" : "=v"(a2) : "v"(p[8 + 2 * j]), "v"(p[9 + 2 * j]));
                asm("v_cvt_pk_bf16_f32 %0, %1, %2" : "=v"(b2) : "v"(p[12 + 2 * j]), "v"(p[13 + 2 * j]));
                asm("v_permlane32_swap_b32 %0, %1" : "+v"(a2), "+v"(b2));
                w[4 + j] = a2; w[6 + j] = b2;
            }
            u32x4 u0 = {w[0], w[1], w[2], w[3]};
            u32x4 u1 = {w[4], w[5], w[6], w[7]};
            short8 pf0 = __builtin_bit_cast(short8, u0);  // k [kb32, kb32+16)
            short8 pf1 = __builtin_bit_cast(short8, u1);  // k [kb32+16, +32)

            // O^T += V^T . P ; L += ones . P (row sums on matrix pipe)
            #pragma unroll
            for (int h = 0; h < 2; ++h) {
                short8 vf0 = *(const short8*)&Vt[buf][h * 32 + l31][(2 * t) * 16 + g * 8];
                Oa[h] = __builtin_amdgcn_mfma_f32_32x32x16_bf16(vf0, pf0, Oa[h], 0, 0, 0);
                short8 vf1 = *(const short8*)&Vt[buf][h * 32 + l31][(2 * t + 1) * 16 + g * 8];
                Oa[h] = __builtin_amdgcn_mfma_f32_32x32x16_bf16(vf1, pf1, Oa[h], 0, 0, 0);
            }
            La = __builtin_amdgcn_mfma_f32_32x32x16_bf16(ones8, pf0, La, 0, 0, 0);
            La = __builtin_amdgcn_mfma_f32_32x32x16_bf16(ones8, pf1, La, 0, 0, 0);
        }

        // stage next tile into the alternate buffer, then ONE barrier
        if (more) {
            *(short8*)&Ks[buf ^ 1][r0][c0] = ka;
            *(short8*)&Ks[buf ^ 1][r1][c0] = kb2;
            *(short8*)&Vt[buf ^ 1][r0][c0] = va;
            *(short8*)&Vt[buf ^ 1][r1][c0] = vb;
        }
        __syncthreads();
        buf ^= 1;
    }

    // epilogue: O^T (regs) -> LDS f32 -> transposed coalesced bf16 store.
    // Reuse Ks/Vt region (all compute done; last barrier passed).
    float* OT = (float*)SMEM;    // [64][132] f32 = 33792 B <= 36864 B
    #pragma unroll
    for (int h = 0; h < 2; ++h)
        #pragma unroll
        for (int r = 0; r < 16; ++r) {
            int hd = h * 32 + (r & 3) + ((r >> 2) << 3) + 4 * g;
            OT[hd * 132 + wave * 32 + l31] = Oa[h][r];
        }
    if (lane < 32) lrow[wave * 32 + l31] = La[0];
    __syncthreads();
    {
        const int q = tid >> 1, hc = (tid & 1) * 32;
        short tmp[32];
        #pragma unroll
        for (int i = 0; i < 32; ++i)
            tmp[i] = f2bf(OT[(hc + i) * 132 + q]);
        #pragma unroll
        for (int v = 0; v < 4; ++v)
            *(short8*)&Ob[q * 64 + hc + v * 8] = *(short8*)&tmp[v * 8];
    }
}

// ---------------------------------------------------------------------------
// Merge: O = (O0 + O1) / (l0 + l1). grid (32 bh, 16 qt), 256 threads.
// Opart slots are [128 q][64 hd] bf16; element-wise, fully coalesced.
// ---------------------------------------------------------------------------
__global__ __launch_bounds__(256) void attn_merge_kernel(
    const short* __restrict__ Opart, const float* __restrict__ lbuf,
    short* __restrict__ AO)
{
    const int bh = blockIdx.x, qt = blockIdx.y;
    const int b = bh >> 4, h = bh & 15;
    const int t = threadIdx.x;
    const int r = t >> 1, hc = (t & 1) * 32;

    const size_t s0 = (size_t)bh * 16 + qt;
    const size_t s1 = (size_t)(32 + bh) * 16 + qt;
    const float inv = 1.0f / (lbuf[s0 * 128 + r] + lbuf[s1 * 128 + r]);

    const size_t o0 = s0 * 8192 + (size_t)r * 64 + hc;
    const size_t o1 = s1 * 8192 + (size_t)r * 64 + hc;
    size_t ab = ((size_t)(b * TT + qt * 128 + r) << 10) + h * 64 + hc;
    #pragma unroll
    for (int v = 0; v < 4; ++v) {
        short8 va = *(const short8*)&Opart[o0 + v * 8];
        short8 vb = *(const short8*)&Opart[o1 + v * 8];
        short8 ov;
        #pragma unroll
        for (int i = 0; i < 8; ++i)
            ov[i] = f2bf((bf2f(va[i]) + bf2f(vb[i])) * inv);
        *(short8*)&AO[ab + v * 8] = ov;
    }
}

// ---------------------------------------------------------------------------
// Fallback single-pass attention (fixed-shift + ones-row l) for small ws.
// ---------------------------------------------------------------------------
__global__ __launch_bounds__(256) void attn_kernel(
    const short* __restrict__ Q, const short* __restrict__ K,
    const short* __restrict__ V, short* __restrict__ AO)
{
    const int j = blockIdx.y, cdeal = j & 7, rdeal = j >> 3;
    const int qtile = (rdeal == 0) ? 31 - cdeal :
                      (rdeal == 1) ? 16 + cdeal :
                      (rdeal == 2) ? 15 - cdeal : cdeal;
    const int bh = blockIdx.x;
    const int qbase = qtile * 64;
    const short* Qp = Q + (size_t)bh * TT * 64;
    const short* Kp = K + (size_t)bh * TT * 64;
    const short* Vp = V + (size_t)bh * 64 * TT;

    __shared__ __align__(16) short Ks[64][72];
    __shared__ __align__(16) short Vt[64][72];
    __shared__ __align__(16) short Ps[4][16][72];

    const int tid = threadIdx.x;
    const int wave = tid >> 6, lane = tid & 63;
    const int lr = lane & 15;
    const int lk = (lane >> 4) * 8;
    const int g4 = (lane >> 4) * 4;
    const int b = bh >> 4, h = bh & 15;

    const int r0 = tid >> 3, c0 = (tid & 7) * 8;
    const int r1 = (tid + 256) >> 3, c1 = c0;

    const int qrowA = qbase + wave * 16 + lr;
    const short8 qf0 = *(const short8*)&Qp[(size_t)qrowA * 64 + lk];
    const short8 qf1 = *(const short8*)&Qp[(size_t)qrowA * 64 + 32 + lk];

    short8 ones8;
    #pragma unroll
    for (int i = 0; i < 8; ++i) ones8[i] = BF16_ONE;

    f32x4 Oa[4] = {{0,0,0,0},{0,0,0,0},{0,0,0,0},{0,0,0,0}};
    f32x4 La = {0, 0, 0, 0};

    {
        *(short8*)&Ks[r0][c0] = *(const short8*)&Kp[(size_t)r0 * 64 + c0];
        *(short8*)&Ks[r1][c1] = *(const short8*)&Kp[(size_t)r1 * 64 + c1];
        *(short8*)&Vt[r0][c0] = *(const short8*)&Vp[(size_t)r0 * TT + c0];
        *(short8*)&Vt[r1][c1] = *(const short8*)&Vp[(size_t)r1 * TT + c1];
    }
    __syncthreads();

    const int kend = qbase + 64;
    for (int kt = 0; kt < kend; kt += 64) {
        const bool more = (kt + 64) < kend;
        short8 ka, kb, va, vb;
        if (more) {
            const int kn = kt + 64;
            ka = *(const short8*)&Kp[(size_t)(kn + r0) * 64 + c0];
            kb = *(const short8*)&Kp[(size_t)(kn + r1) * 64 + c1];
            va = *(const short8*)&Vp[(size_t)r0 * TT + kn + c0];
            vb = *(const short8*)&Vp[(size_t)r1 * TT + kn + c1];
        }

        f32x4 s[4];
        #pragma unroll
        for (int c = 0; c < 4; ++c) {
            f32x4 z = {0, 0, 0, 0};
            short8 k0v = *(const short8*)&Ks[c * 16 + lr][lk];
            short8 k1v = *(const short8*)&Ks[c * 16 + lr][32 + lk];
            z = __builtin_amdgcn_mfma_f32_16x16x32_bf16(k0v, qf0, z, 0, 0, 0);
            z = __builtin_amdgcn_mfma_f32_16x16x32_bf16(k1v, qf1, z, 0, 0, 0);
            s[c] = z;
        }

        const bool diag = (kt == qbase);
        #pragma unroll
        for (int c = 0; c < 4; ++c) {
            ushort4v pk;
            #pragma unroll
            for (int i = 0; i < 4; ++i) {
                float arg = s[c][i] * SCALE_LOG2 - FSHIFT;
                if (diag) {
                    int colg = kt + c * 16 + g4 + i;
                    if (colg > qrowA) arg = NEG_BIG;
                }
                pk[i] = (unsigned short)f2bf(fast_exp2(arg));
            }
            *(ushort4v*)&Ps[wave][lr][c * 16 + g4] = pk;
        }

        #pragma unroll
        for (int kk = 0; kk < 2; ++kk) {
            short8 af = *(const short8*)&Ps[wave][lr][kk * 32 + lk];
            #pragma unroll
            for (int c = 0; c < 4; ++c) {
                short8 bf = *(const short8*)&Vt[c * 16 + lr][kk * 32 + lk];
                Oa[c] = __builtin_amdgcn_mfma_f32_16x16x32_bf16(af, bf, Oa[c], 0, 0, 0);
            }
            La = __builtin_amdgcn_mfma_f32_16x16x32_bf16(af, ones8, La, 0, 0, 0);
        }
        __syncthreads();

        if (more) {
            *(short8*)&Ks[r0][c0] = ka;
            *(short8*)&Ks[r1][c1] = kb;
            *(short8*)&Vt[r0][c0] = va;
            *(short8*)&Vt[r1][c1] = vb;
            __syncthreads();
        }
    }

    #pragma unroll
    for (int c = 0; c < 4; ++c) {
        #pragma unroll
        for (int i = 0; i < 4; ++i) {
            int qr = qbase + wave * 16 + g4 + i;
            float v = Oa[c][i] / La[i];
            AO[((size_t)(b * TT + qr) << 10) + h * 64 + c * 16 + lr] = f2bf(v);
        }
    }
}

// ---------------------------------------------------------------------------
extern "C" void kernel_launch(void* const* d_in, const int* in_sizes, int n_in,
                              void* d_out, int out_size, void* d_ws, size_t ws_size,
                              hipStream_t stream)
{
    char* ws = (char*)d_ws;
    const size_t XB  = (size_t)TM * TD * 2;   // 8 MiB bf16 x
    const size_t WB  = (size_t)TD * TD * 2;   // 2 MiB bf16 weight
    const size_t BUF = (size_t)TM * TD * 2;   // 8 MiB activation

    short* xb  = (short*)(ws + 256);
    short* Wqb = (short*)(ws + 256 + XB);
    short* Wkb = (short*)(ws + 256 + XB + WB);
    short* Wvb = (short*)(ws + 256 + XB + 2 * WB);
    short* Wob = (short*)(ws + 256 + XB + 3 * WB);
    char*  act = ws + 256 + XB + 4 * WB;
    short* Qb = (short*)(act);
    short* Kb = (short*)(act + BUF);
    short* Vb = (short*)(act + 2 * BUF);   // V^T [B,H,64,T]
    short* Ab = (short*)(act + 3 * BUF);
    char*  part = act + 4 * BUF;
    short* Opart = (short*)part;                               // 16 MiB
    float* lbuf  = (float*)(part + (size_t)16 * 1024 * 1024);  // 512 KiB

    const size_t need = 256 + XB + 4 * WB + 4 * BUF +
                        (size_t)16 * 1024 * 1024 + 524288;
    const bool splitS = (ws_size >= need);   // constant across calls: graph-safe

    dim3 blk(256);
    convert_all_kernel<<<dim3(512 + 4 * 128), blk, 0, stream>>>(
        d_in[0], d_in[1], d_in[2], d_in[3], d_in[4], xb, Wqb, Wkb, Wvb, Wob);
    qkv_gemm_kernel<<<dim3(TM / 128, TD / 128, 3), blk, 0, stream>>>(xb, Wqb, Wkb, Wvb, Qb, Kb, Vb);
    if (splitS) {
        attn_split_kernel<<<dim3(32, 32), blk, 0, stream>>>(Qb, Kb, Vb, Opart, lbuf);
        attn_merge_kernel<<<dim3(32, 16), blk, 0, stream>>>(Opart, lbuf, Ab);
    } else {
        attn_kernel<<<dim3(32, 32), blk, 0, stream>>>(Qb, Kb, Vb, Ab);
    }
    out_gemm_kernel<<<dim3(TM / 64, TD / 128), blk, 0, stream>>>(
        Ab, Wob, d_out, (const unsigned short*)d_in[0]);
}

// Round 2
// 177.527 us; speedup vs baseline: 1.0424x; 1.0290x over previous
//
#include <hip/hip_runtime.h>
#include <hip/hip_bf16.h>

// Problem: B=2, T=2048, D=1024, H=16, HD=64.
// Runtime-detect fp32 vs bf16 inputs (inline, per-wave); canonicalize to bf16.
// convert_all -> qkv gemm (128x128, global_load_lds staging m97-style;
// Q,K:[B,H,T,64] via LDS-transpose epilogue; V:[B,H,64,T]) -> split-S flash
// attention (32x32 MFMA, swapped QK^T, in-register softmax via cvt_pk_bf16 +
// permlane32_swap, fixed-shift softmax, K/V LDS double-buffer w/ 1 barrier/
// tile, MFMA ones-row l, setprio around MFMA) -> merge -> out gemm (64x128).

#define TB 2
#define TT 2048
#define TD 1024
#define TH 16
#define TM (TB * TT) // 4096

#define NEG_BIG (-1e30f)
#define SCALE_LOG2 0.18033688f  // (1/sqrt(64)) * log2(e)
#define FSHIFT 16.0f            // fixed softmax shift (exact; cancels in O/l)
#define BF16_ONE ((short)0x3F80)

typedef __attribute__((ext_vector_type(8))) short short8;
typedef __attribute__((ext_vector_type(4))) float f32x4;
typedef __attribute__((ext_vector_type(16))) float f32x16;
typedef __attribute__((ext_vector_type(4))) unsigned short ushort4v;
typedef __attribute__((ext_vector_type(4))) unsigned int u32x4;

__device__ __forceinline__ short f2bf(float f) {
    __hip_bfloat16 h = __float2bfloat16(f);
    return __builtin_bit_cast(short, h);
}

__device__ __forceinline__ float bf2f(short u) {
    unsigned int x = ((unsigned int)(unsigned short)u) << 16;
    return __builtin_bit_cast(float, x);
}

__device__ __forceinline__ float fast_exp2(float x) {
#if __has_builtin(__builtin_amdgcn_exp2f)
    return __builtin_amdgcn_exp2f(x);
#else
    return exp2f(x);
#endif
}

__device__ __forceinline__ f32x16 zero16() {
    f32x16 v;
    #pragma unroll
    for (int i = 0; i < 16; ++i) v[i] = 0.f;
    return v;
}

// Async global->LDS DMA, 16 B/lane. LDS dest is wave-uniform base + lane*16;
// global src is per-lane (pre-swizzled). Completion counted by vmcnt; the
// compiler's s_waitcnt vmcnt(0) before s_barrier (__syncthreads) drains it.
__device__ __forceinline__ void gload_lds16(const short* g, short* l) {
    __builtin_amdgcn_global_load_lds(
        (const __attribute__((address_space(1))) unsigned int*)g,
        (__attribute__((address_space(3))) unsigned int*)l,
        16, 0, 0);
}

// Inline dtype detect: sample even u16s of x; uniform per wave.
__device__ __forceinline__ int detect_bf16(const unsigned short* xq) {
    int lane = threadIdx.x & 63;
    unsigned short u = xq[lane * 2];
    int e = (u >> 7) & 0xFF;
    int sane = ((e >= 100 && e <= 145) || u == 0) ? 1 : 0;
    unsigned long long b = __ballot(sane);
    return (__popcll(b) >= 48) ? 1 : 0; // 1 = bf16, 0 = fp32
}

// ---------------------------------------------------------------------------
// One dispatch converts x + 4 weights; 8192 elems/block.
// ---------------------------------------------------------------------------
__global__ __launch_bounds__(256) void convert_all_kernel(
    const void* __restrict__ x,  const void* __restrict__ wq,
    const void* __restrict__ wk, const void* __restrict__ wv,
    const void* __restrict__ wo,
    short* __restrict__ xb, short* __restrict__ wqb, short* __restrict__ wkb,
    short* __restrict__ wvb, short* __restrict__ wob)
{
    const int f = detect_bf16((const unsigned short*)x);
    int bid = blockIdx.x;
    const void* src; short* dst; int base;
    if (bid < 512) { src = x; dst = xb; base = bid; }
    else {
        int w = (bid - 512) >> 7, lb = (bid - 512) & 127;
        src = (w == 0) ? wq : (w == 1) ? wk : (w == 2) ? wv : wo;
        dst = (w == 0) ? wqb : (w == 1) ? wkb : (w == 2) ? wvb : wob;
        base = lb;
    }
    int i0 = base * 8192 + (int)threadIdx.x * 8;
    #pragma unroll
    for (int r = 0; r < 4; ++r) {
        int i = i0 + r * 2048;
        if (f) {
            *(short8*)(dst + i) = *(const short8*)((const short*)src + i);
        } else {
            const float* s = (const float*)src + i;
            short8 o;
            #pragma unroll
            for (int j = 0; j < 8; ++j) o[j] = f2bf(s[j]);
            *(short8*)(dst + i) = o;
        }
    }
}

// ---------------------------------------------------------------------------
// GEMM core, global_load_lds staging (m97 structure). C[m,n]=sum_k A[m,k]B[n,k].
// Tile: MROWS x 128, BK=64, K=1024. 4 waves (2x2). XOR chunk swizzle folded
// into the per-lane GLOBAL source address; LDS writes stay linear (lane*16B).
// Per K-step: {loads issued in the prior gap} -> barrier -> ds_read+MFMA ->
// barrier -> issue next loads.
// ---------------------------------------------------------------------------
template<int MROWS>
__device__ __forceinline__ void gemm_core_lds(
    const short* __restrict__ A, const short* __restrict__ B,
    short* SM, int mbase, int nbase, f32x4 (*acc)[4])
{
    constexpr int TA = MROWS / 32;
    short* As = SM;
    short* Bs = SM + MROWS * 64;

    const int tid = threadIdx.x;
    const int wave = tid >> 6, lane = tid & 63;
    const int wm = wave >> 1, wn = wave & 1;
    const int lr = lane & 15;
    const int srow = lane >> 3, jcl = lane & 7;
    const int jc = (jcl ^ srow) * 8;   // (r&7)==srow for all staged rows

    #pragma unroll
    for (int a = 0; a < TA; ++a)
        #pragma unroll
        for (int b = 0; b < 4; ++b) acc[a][b] = (f32x4){0, 0, 0, 0};

    const short* aA[TA]; short* lA[TA];
    const short* aB[4];  short* lB[4];
    #pragma unroll
    for (int t = 0; t < TA; ++t) {
        int w = wave * TA + t;
        aA[t] = A + (size_t)(mbase + w * 8 + srow) * TD + jc;
        lA[t] = As + w * 512;
    }
    #pragma unroll
    for (int t = 0; t < 4; ++t) {
        int w = wave * 4 + t;
        aB[t] = B + (size_t)(nbase + w * 8 + srow) * TD + jc;
        lB[t] = Bs + w * 512;
    }

    // prologue: issue k0=0 tile
    #pragma unroll
    for (int t = 0; t < TA; ++t) gload_lds16(aA[t], lA[t]);
    #pragma unroll
    for (int t = 0; t < 4; ++t)  gload_lds16(aB[t], lB[t]);

    for (int k0 = 0; k0 < TD; k0 += 64) {
        __syncthreads();   // staged loads complete (vmcnt drained per-wave)
        #pragma unroll
        for (int kk = 0; kk < 64; kk += 32) {
            const int cc = (kk >> 3) + (lane >> 4);
            const int csw = (cc ^ (lr & 7)) << 3;
            short8 af[TA], bf[4];
            #pragma unroll
            for (int a = 0; a < TA; ++a)
                af[a] = *(const short8*)&As[(wm * (MROWS / 2) + a * 16 + lr) * 64 + csw];
            #pragma unroll
            for (int b = 0; b < 4; ++b)
                bf[b] = *(const short8*)&Bs[(wn * 64 + b * 16 + lr) * 64 + csw];
            #pragma unroll
            for (int a = 0; a < TA; ++a)
                #pragma unroll
                for (int b = 0; b < 4; ++b)
                    acc[a][b] = __builtin_amdgcn_mfma_f32_16x16x32_bf16(af[a], bf[b], acc[a][b], 0, 0, 0);
        }
        if (k0 + 64 < TD) {
            __syncthreads();   // all LDS reads done; safe to overwrite
            #pragma unroll
            for (int t = 0; t < TA; ++t) gload_lds16(aA[t] + k0 + 64, lA[t]);
            #pragma unroll
            for (int t = 0; t < 4; ++t)  gload_lds16(aB[t] + k0 + 64, lB[t]);
        }
    }
}

// ---------------------------------------------------------------------------
// QKV projection; 128x128 tiles, grid (32, 8, 3).
// Q,K out [B,H,T,64] via LDS-transposed coalesced epilogue; V out [B,H,64,T].
// ---------------------------------------------------------------------------
__global__ __launch_bounds__(256, 3) void qkv_gemm_kernel(
    const short* __restrict__ x,
    const short* __restrict__ Wq, const short* __restrict__ Wk,
    const short* __restrict__ Wv,
    short* __restrict__ Qo, short* __restrict__ Ko, short* __restrict__ Vo)
{
    const short* W = (blockIdx.z == 0) ? Wq : (blockIdx.z == 1) ? Wk : Wv;
    short* Out = (blockIdx.z == 0) ? Qo : (blockIdx.z == 1) ? Ko : Vo;
    const bool transposeV = (blockIdx.z == 2);

    __shared__ __align__(16) short SM[128 * 64 * 2];

    const int mbase = blockIdx.x * 128, nbase = blockIdx.y * 128;
    f32x4 acc[4][4];
    gemm_core_lds<128>(x, W, SM, mbase, nbase, acc);

    const int tid = threadIdx.x;
    const int wave = tid >> 6, lane = tid & 63;
    const int wm = wave >> 1, wn = wave & 1;
    const int lr = lane & 15;
    const int g4 = (lane >> 4) * 4;

    if (transposeV) {
        #pragma unroll
        for (int a = 0; a < 4; ++a) {
            #pragma unroll
            for (int b = 0; b < 4; ++b) {
                int m0 = mbase + wm * 64 + a * 16 + g4;
                int n = nbase + wn * 64 + b * 16 + lr;
                int bb = m0 >> 11, t0 = m0 & (TT - 1);
                int h = n >> 6, hd = n & 63;
                ushort4v pk;
                #pragma unroll
                for (int i = 0; i < 4; ++i) pk[i] = (unsigned short)f2bf(acc[a][b][i]);
                *(ushort4v*)&Out[((size_t)(bb * TH + h) * 64 + hd) * TT + t0] = pk;
            }
        }
    } else {
        short* Cs = SM;
        #pragma unroll
        for (int p = 0; p < 2; ++p) {
            __syncthreads();
            if (wn == p) {
                #pragma unroll
                for (int a = 0; a < 4; ++a)
                    #pragma unroll
                    for (int b = 0; b < 4; ++b)
                        #pragma unroll
                        for (int i = 0; i < 4; ++i) {
                            int ml = wm * 64 + a * 16 + g4 + i;
                            int nl = b * 16 + lr;
                            Cs[ml * 72 + nl] = f2bf(acc[a][b][i]);
                        }
            }
            __syncthreads();
            int tl = tid >> 1, hc = (tid & 1) * 32;
            int h = (nbase >> 6) + p;
            int m = mbase + tl;
            int bb = m >> 11, t = m & (TT - 1);
            size_t base = (((size_t)(bb * TH + h) * TT + t) << 6) + hc;
            #pragma unroll
            for (int q = 0; q < 4; ++q)
                *(short8*)&Out[base + q * 8] = *(short8*)&Cs[tl * 72 + hc + q * 8];
        }
    }
}

// ---------------------------------------------------------------------------
// Output projection; 64x128 tiles, grid (64, 8).
// ---------------------------------------------------------------------------
__global__ __launch_bounds__(256, 2) void out_gemm_kernel(
    const short* __restrict__ A, const short* __restrict__ W,
    void* __restrict__ C, const unsigned short* __restrict__ xq)
{
    const int f = detect_bf16(xq);

    __shared__ __align__(16) short SM[64 * 64 + 128 * 64];

    const int mbase = blockIdx.x * 64, nbase = blockIdx.y * 128;
    f32x4 acc[2][4];
    gemm_core_lds<64>(A, W, SM, mbase, nbase, acc);

    const int tid = threadIdx.x;
    const int wave = tid >> 6, lane = tid & 63;
    const int wm = wave >> 1, wn = wave & 1;
    const int lr = lane & 15;
    const int g4 = (lane >> 4) * 4;

    #pragma unroll
    for (int a = 0; a < 2; ++a) {
        #pragma unroll
        for (int b = 0; b < 4; ++b) {
            #pragma unroll
            for (int i = 0; i < 4; ++i) {
                int m = mbase + wm * 32 + a * 16 + g4 + i;
                int n = nbase + wn * 64 + b * 16 + lr;
                if (f) ((short*)C)[(size_t)m * TD + n] = f2bf(acc[a][b][i]);
                else   ((float*)C)[(size_t)m * TD + n] = acc[a][b][i];
            }
        }
    }
}

// ---------------------------------------------------------------------------
// Split-S flash attention, 32x32 MFMA, swapped QK^T (S^T = K Q^T), softmax
// fully in registers, P->bf16 via v_cvt_pk_bf16_f32 + v_permlane32_swap_b32,
// l on the MFMA pipe via ones-A-frag. 128 q-rows/block (4 waves x 32 q-rows),
// K/V LDS double-buffer, ONE barrier per 64-k tile. grid (32 bh, 32 work).
// setprio(1) around MFMA clusters (T5).
// ---------------------------------------------------------------------------
__global__ __launch_bounds__(256, 3) void attn_split_kernel(
    const short* __restrict__ Q, const short* __restrict__ K,
    const short* __restrict__ V, short* __restrict__ Opart,
    float* __restrict__ lbuf)
{
    const int bh = blockIdx.x;
    const int y = blockIdx.y;
    const int qt = 15 - (y >> 1);
    const int half = y & 1;
    const int nt0 = qt + 1;
    const int tb = half ? nt0 : 0;
    const int te = half ? (2 * qt + 2) : nt0;

    const int qbase = qt * 128;
    const short* Qp = Q + (size_t)bh * TT * 64;
    const short* Kp = K + (size_t)bh * TT * 64;
    const short* Vp = V + (size_t)bh * 64 * TT;   // V^T: [64][TT]

    __shared__ __align__(16) short SMEM[18432];   // Ks[2][64][72] | Vt[2][64][72]
    short (*Ks)[64][72] = (short (*)[64][72])(SMEM);
    short (*Vt)[64][72] = (short (*)[64][72])(SMEM + 9216);

    const int tid = threadIdx.x;
    const int wave = tid >> 6, lane = tid & 63;
    const int l31 = lane & 31, g = lane >> 5;

    const size_t pslot = (size_t)((half * 32 + bh) * 16 + qt);
    float* lrow = lbuf + pslot * 128;
    short* Ob = Opart + pslot * 8192;

    // staging coords: each thread stages 2 K rows + 2 V rows, 16B each
    const int r0 = tid >> 3, c0 = (tid & 7) * 8;
    const int r1 = r0 + 32;

    // Q fragments (B-operand): lane holds q-row qrow, 64 hd in 4 chunks
    const int qrow0 = qbase + wave * 32;      // wave's min q (uniform)
    const int qrow = qrow0 + l31;             // this lane's q row
    short8 qf[4];
    #pragma unroll
    for (int c = 0; c < 4; ++c)
        qf[c] = *(const short8*)&Qp[(size_t)qrow * 64 + c * 16 + g * 8];

    short8 ones8;
    #pragma unroll
    for (int i = 0; i < 8; ++i) ones8[i] = BF16_ONE;

    f32x16 Oa[2];                // O^T accum: [hd-tile][ (hd-row, q) frag ]
    Oa[0] = zero16(); Oa[1] = zero16();
    f32x16 La = zero16();        // l (all 32 rows identical = l[q])

    // prologue: stage first tile into buf 0
    {
        const int kb = tb * 64;
        *(short8*)&Ks[0][r0][c0] = *(const short8*)&Kp[(size_t)(kb + r0) * 64 + c0];
        *(short8*)&Ks[0][r1][c0] = *(const short8*)&Kp[(size_t)(kb + r1) * 64 + c0];
        *(short8*)&Vt[0][r0][c0] = *(const short8*)&Vp[(size_t)r0 * TT + kb + c0];
        *(short8*)&Vt[0][r1][c0] = *(const short8*)&Vp[(size_t)r1 * TT + kb + c0];
    }
    __syncthreads();

    int buf = 0;
    for (int it = tb; it < te; ++it) {
        const int kt = it * 64;
        const bool more = (it + 1) < te;
        short8 ka, kb2, va, vb;
        if (more) {
            const int kn = kt + 64;
            ka  = *(const short8*)&Kp[(size_t)(kn + r0) * 64 + c0];
            kb2 = *(const short8*)&Kp[(size_t)(kn + r1) * 64 + c0];
            va  = *(const short8*)&Vp[(size_t)r0 * TT + kn + c0];
            vb  = *(const short8*)&Vp[(size_t)r1 * TT + kn + c0];
        }

        #pragma unroll
        for (int t = 0; t < 2; ++t) {
            const int kb32 = kt + t * 32;
            if (kb32 > qrow0 + 31) continue;   // fully masked (wave-uniform)

            // S^T subtile = K(32 k-rows) . Q^T, accumulate over hd
            f32x16 S = zero16();
            __builtin_amdgcn_s_setprio(1);
            #pragma unroll
            for (int c = 0; c < 4; ++c) {
                short8 kf = *(const short8*)&Ks[buf][t * 32 + l31][c * 16 + g * 8];
                S = __builtin_amdgcn_mfma_f32_32x32x16_bf16(kf, qf[c], S, 0, 0, 0);
            }
            __builtin_amdgcn_s_setprio(0);

            // P = 2^(S*scale - 16); causal mask -> 0 (exact fixed-shift)
            float p[16];
            const bool partm = (kb32 + 31) > qrow0;
            if (partm) {
                #pragma unroll
                for (int r = 0; r < 16; ++r) {
                    int kglob = kb32 + (r & 3) + ((r >> 2) << 3) + 4 * g;
                    float arg = S[r] * SCALE_LOG2 - FSHIFT;
                    p[r] = fast_exp2(kglob > qrow ? NEG_BIG : arg);
                }
            } else {
                #pragma unroll
                for (int r = 0; r < 16; ++r)
                    p[r] = fast_exp2(S[r] * SCALE_LOG2 - FSHIFT);
            }

            // pack to bf16 B-fragments in-register (T12):
            // word(c2,j): lane-half g holds k-pair {16c2+8g+2j, +1}
            unsigned int w[8];
            #pragma unroll
            for (int j = 0; j < 2; ++j) {
                unsigned int a, b;
                asm("v_cvt_pk_bf16_f32 %0, %1, %2" : "=v"(a) : "v"(p[2 * j]), "v"(p[2 * j + 1]));
                asm("v_cvt_pk_bf16_f32 %0, %1, %2" : "=v"(b) : "v"(p[2 * j + 4]), "v"(p[2 * j + 5]));
                asm("v_permlane32_swap_b32 %0, %1" : "+v"(a), "+v"(b));
                w[j] = a; w[j + 2] = b;
                unsigned int a2, b2;
                asm("v_cvt_pk_bf16_f32 %0, %1, %2" : "=v"(a2) : "v"(p[8 + 2 * j]), "v"(p[9 + 2 * j]));
                asm("v_cvt_pk_bf16_f32 %0, %1, %2" : "=v"(b2) : "v"(p[12 + 2 * j]), "v"(p[13 + 2 * j]));
                asm("v_permlane32_swap_b32 %0, %1" : "+v"(a2), "+v"(b2));
                w[4 + j] = a2; w[6 + j] = b2;
            }
            u32x4 u0 = {w[0], w[1], w[2], w[3]};
            u32x4 u1 = {w[4], w[5], w[6], w[7]};
            short8 pf0 = __builtin_bit_cast(short8, u0);  // k [kb32, kb32+16)
            short8 pf1 = __builtin_bit_cast(short8, u1);  // k [kb32+16, +32)

            // O^T += V^T . P ; L += ones . P (row sums on matrix pipe)
            __builtin_amdgcn_s_setprio(1);
            #pragma unroll
            for (int h = 0; h < 2; ++h) {
                short8 vf0 = *(const short8*)&Vt[buf][h * 32 + l31][(2 * t) * 16 + g * 8];
                Oa[h] = __builtin_amdgcn_mfma_f32_32x32x16_bf16(vf0, pf0, Oa[h], 0, 0, 0);
                short8 vf1 = *(const short8*)&Vt[buf][h * 32 + l31][(2 * t + 1) * 16 + g * 8];
                Oa[h] = __builtin_amdgcn_mfma_f32_32x32x16_bf16(vf1, pf1, Oa[h], 0, 0, 0);
            }
            La = __builtin_amdgcn_mfma_f32_32x32x16_bf16(ones8, pf0, La, 0, 0, 0);
            La = __builtin_amdgcn_mfma_f32_32x32x16_bf16(ones8, pf1, La, 0, 0, 0);
            __builtin_amdgcn_s_setprio(0);
        }

        // stage next tile into the alternate buffer, then ONE barrier
        if (more) {
            *(short8*)&Ks[buf ^ 1][r0][c0] = ka;
            *(short8*)&Ks[buf ^ 1][r1][c0] = kb2;
            *(short8*)&Vt[buf ^ 1][r0][c0] = va;
            *(short8*)&Vt[buf ^ 1][r1][c0] = vb;
        }
        __syncthreads();
        buf ^= 1;
    }

    // epilogue: O^T (regs) -> LDS f32 -> transposed coalesced bf16 store.
    // Reuse Ks/Vt region (all compute done; last barrier passed).
    float* OT = (float*)SMEM;    // [64][132] f32 = 33792 B <= 36864 B
    #pragma unroll
    for (int h = 0; h < 2; ++h)
        #pragma unroll
        for (int r = 0; r < 16; ++r) {
            int hd = h * 32 + (r & 3) + ((r >> 2) << 3) + 4 * g;
            OT[hd * 132 + wave * 32 + l31] = Oa[h][r];
        }
    if (lane < 32) lrow[wave * 32 + l31] = La[0];
    __syncthreads();
    {
        const int q = tid >> 1, hc = (tid & 1) * 32;
        short tmp[32];
        #pragma unroll
        for (int i = 0; i < 32; ++i)
            tmp[i] = f2bf(OT[(hc + i) * 132 + q]);
        #pragma unroll
        for (int v = 0; v < 4; ++v)
            *(short8*)&Ob[q * 64 + hc + v * 8] = *(short8*)&tmp[v * 8];
    }
}

// ---------------------------------------------------------------------------
// Merge: O = (O0 + O1) / (l0 + l1). grid (32 bh, 16 qt), 256 threads.
// Opart slots are [128 q][64 hd] bf16; element-wise, fully coalesced.
// ---------------------------------------------------------------------------
__global__ __launch_bounds__(256) void attn_merge_kernel(
    const short* __restrict__ Opart, const float* __restrict__ lbuf,
    short* __restrict__ AO)
{
    const int bh = blockIdx.x, qt = blockIdx.y;
    const int b = bh >> 4, h = bh & 15;
    const int t = threadIdx.x;
    const int r = t >> 1, hc = (t & 1) * 32;

    const size_t s0 = (size_t)bh * 16 + qt;
    const size_t s1 = (size_t)(32 + bh) * 16 + qt;
    const float inv = 1.0f / (lbuf[s0 * 128 + r] + lbuf[s1 * 128 + r]);

    const size_t o0 = s0 * 8192 + (size_t)r * 64 + hc;
    const size_t o1 = s1 * 8192 + (size_t)r * 64 + hc;
    size_t ab = ((size_t)(b * TT + qt * 128 + r) << 10) + h * 64 + hc;
    #pragma unroll
    for (int v = 0; v < 4; ++v) {
        short8 va = *(const short8*)&Opart[o0 + v * 8];
        short8 vb = *(const short8*)&Opart[o1 + v * 8];
        short8 ov;
        #pragma unroll
        for (int i = 0; i < 8; ++i)
            ov[i] = f2bf((bf2f(va[i]) + bf2f(vb[i])) * inv);
        *(short8*)&AO[ab + v * 8] = ov;
    }
}

// ---------------------------------------------------------------------------
// Fallback single-pass attention (fixed-shift + ones-row l) for small ws.
// ---------------------------------------------------------------------------
__global__ __launch_bounds__(256) void attn_kernel(
    const short* __restrict__ Q, const short* __restrict__ K,
    const short* __restrict__ V, short* __restrict__ AO)
{
    const int j = blockIdx.y, cdeal = j & 7, rdeal = j >> 3;
    const int qtile = (rdeal == 0) ? 31 - cdeal :
                      (rdeal == 1) ? 16 + cdeal :
                      (rdeal == 2) ? 15 - cdeal : cdeal;
    const int bh = blockIdx.x;
    const int qbase = qtile * 64;
    const short* Qp = Q + (size_t)bh * TT * 64;
    const short* Kp = K + (size_t)bh * TT * 64;
    const short* Vp = V + (size_t)bh * 64 * TT;

    __shared__ __align__(16) short Ks[64][72];
    __shared__ __align__(16) short Vt[64][72];
    __shared__ __align__(16) short Ps[4][16][72];

    const int tid = threadIdx.x;
    const int wave = tid >> 6, lane = tid & 63;
    const int lr = lane & 15;
    const int lk = (lane >> 4) * 8;
    const int g4 = (lane >> 4) * 4;
    const int b = bh >> 4, h = bh & 15;

    const int r0 = tid >> 3, c0 = (tid & 7) * 8;
    const int r1 = (tid + 256) >> 3, c1 = c0;

    const int qrowA = qbase + wave * 16 + lr;
    const short8 qf0 = *(const short8*)&Qp[(size_t)qrowA * 64 + lk];
    const short8 qf1 = *(const short8*)&Qp[(size_t)qrowA * 64 + 32 + lk];

    short8 ones8;
    #pragma unroll
    for (int i = 0; i < 8; ++i) ones8[i] = BF16_ONE;

    f32x4 Oa[4] = {{0,0,0,0},{0,0,0,0},{0,0,0,0},{0,0,0,0}};
    f32x4 La = {0, 0, 0, 0};

    {
        *(short8*)&Ks[r0][c0] = *(const short8*)&Kp[(size_t)r0 * 64 + c0];
        *(short8*)&Ks[r1][c1] = *(const short8*)&Kp[(size_t)r1 * 64 + c1];
        *(short8*)&Vt[r0][c0] = *(const short8*)&Vp[(size_t)r0 * TT + c0];
        *(short8*)&Vt[r1][c1] = *(const short8*)&Vp[(size_t)r1 * TT + c1];
    }
    __syncthreads();

    const int kend = qbase + 64;
    for (int kt = 0; kt < kend; kt += 64) {
        const bool more = (kt + 64) < kend;
        short8 ka, kb, va, vb;
        if (more) {
            const int kn = kt + 64;
            ka = *(const short8*)&Kp[(size_t)(kn + r0) * 64 + c0];
            kb = *(const short8*)&Kp[(size_t)(kn + r1) * 64 + c1];
            va = *(const short8*)&Vp[(size_t)r0 * TT + kn + c0];
            vb = *(const short8*)&Vp[(size_t)r1 * TT + kn + c1];
        }

        f32x4 s[4];
        #pragma unroll
        for (int c = 0; c < 4; ++c) {
            f32x4 z = {0, 0, 0, 0};
            short8 k0v = *(const short8*)&Ks[c * 16 + lr][lk];
            short8 k1v = *(const short8*)&Ks[c * 16 + lr][32 + lk];
            z = __builtin_amdgcn_mfma_f32_16x16x32_bf16(k0v, qf0, z, 0, 0, 0);
            z = __builtin_amdgcn_mfma_f32_16x16x32_bf16(k1v, qf1, z, 0, 0, 0);
            s[c] = z;
        }

        const bool diag = (kt == qbase);
        #pragma unroll
        for (int c = 0; c < 4; ++c) {
            ushort4v pk;
            #pragma unroll
            for (int i = 0; i < 4; ++i) {
                float arg = s[c][i] * SCALE_LOG2 - FSHIFT;
                if (diag) {
                    int colg = kt + c * 16 + g4 + i;
                    if (colg > qrowA) arg = NEG_BIG;
                }
                pk[i] = (unsigned short)f2bf(fast_exp2(arg));
            }
            *(ushort4v*)&Ps[wave][lr][c * 16 + g4] = pk;
        }

        #pragma unroll
        for (int kk = 0; kk < 2; ++kk) {
            short8 af = *(const short8*)&Ps[wave][lr][kk * 32 + lk];
            #pragma unroll
            for (int c = 0; c < 4; ++c) {
                short8 bf = *(const short8*)&Vt[c * 16 + lr][kk * 32 + lk];
                Oa[c] = __builtin_amdgcn_mfma_f32_16x16x32_bf16(af, bf, Oa[c], 0, 0, 0);
            }
            La = __builtin_amdgcn_mfma_f32_16x16x32_bf16(af, ones8, La, 0, 0, 0);
        }
        __syncthreads();

        if (more) {
            *(short8*)&Ks[r0][c0] = ka;
            *(short8*)&Ks[r1][c1] = kb;
            *(short8*)&Vt[r0][c0] = va;
            *(short8*)&Vt[r1][c1] = vb;
            __syncthreads();
        }
    }

    #pragma unroll
    for (int c = 0; c < 4; ++c) {
        #pragma unroll
        for (int i = 0; i < 4; ++i) {
            int qr = qbase + wave * 16 + g4 + i;
            float v = Oa[c][i] / La[i];
            AO[((size_t)(b * TT + qr) << 10) + h * 64 + c * 16 + lr] = f2bf(v);
        }
    }
}

// ---------------------------------------------------------------------------
extern "C" void kernel_launch(void* const* d_in, const int* in_sizes, int n_in,
                              void* d_out, int out_size, void* d_ws, size_t ws_size,
                              hipStream_t stream)
{
    char* ws = (char*)d_ws;
    const size_t XB  = (size_t)TM * TD * 2;   // 8 MiB bf16 x
    const size_t WB  = (size_t)TD * TD * 2;   // 2 MiB bf16 weight
    const size_t BUF = (size_t)TM * TD * 2;   // 8 MiB activation

    short* xb  = (short*)(ws + 256);
    short* Wqb = (short*)(ws + 256 + XB);
    short* Wkb = (short*)(ws + 256 + XB + WB);
    short* Wvb = (short*)(ws + 256 + XB + 2 * WB);
    short* Wob = (short*)(ws + 256 + XB + 3 * WB);
    char*  act = ws + 256 + XB + 4 * WB;
    short* Qb = (short*)(act);
    short* Kb = (short*)(act + BUF);
    short* Vb = (short*)(act + 2 * BUF);   // V^T [B,H,64,T]
    short* Ab = (short*)(act + 3 * BUF);
    char*  part = act + 4 * BUF;
    short* Opart = (short*)part;                               // 16 MiB
    float* lbuf  = (float*)(part + (size_t)16 * 1024 * 1024);  // 512 KiB

    const size_t need = 256 + XB + 4 * WB + 4 * BUF +
                        (size_t)16 * 1024 * 1024 + 524288;
    const bool splitS = (ws_size >= need);   // constant across calls: graph-safe

    dim3 blk(256);
    convert_all_kernel<<<dim3(512 + 4 * 128), blk, 0, stream>>>(
        d_in[0], d_in[1], d_in[2], d_in[3], d_in[4], xb, Wqb, Wkb, Wvb, Wob);
    qkv_gemm_kernel<<<dim3(TM / 128, TD / 128, 3), blk, 0, stream>>>(xb, Wqb, Wkb, Wvb, Qb, Kb, Vb);
    if (splitS) {
        attn_split_kernel<<<dim3(32, 32), blk, 0, stream>>>(Qb, Kb, Vb, Opart, lbuf);
        attn_merge_kernel<<<dim3(32, 16), blk, 0, stream>>>(Opart, lbuf, Ab);
    } else {
        attn_kernel<<<dim3(32, 32), blk, 0, stream>>>(Qb, Kb, Vb, Ab);
    }
    out_gemm_kernel<<<dim3(TM / 64, TD / 128), blk, 0, stream>>>(
        Ab, Wob, d_out, (const unsigned short*)d_in[0]);
}

// Round 3
// 176.822 us; speedup vs baseline: 1.0465x; 1.0040x over previous
//
#include <hip/hip_runtime.h>
#include <hip/hip_bf16.h>

// Problem: B=2, T=2048, D=1024, H=16, HD=64.
// Runtime-detect fp32 vs bf16 inputs (inline, per-wave); canonicalize to bf16.
// convert_all -> qkv gemm (128x128, global_load_lds staging m97-style;
// Q,K:[B,H,T,64] via LDS-transpose epilogue; V:[B,H,64,T]) -> split-S flash
// attention (32x32 MFMA, swapped QK^T, in-register softmax via cvt_pk_bf16 +
// permlane32_swap, fixed-shift softmax, K/V LDS double-buffer w/ 1 barrier/
// tile, MFMA ones-row l, setprio, 4 blocks/CU) -> merge -> out gemm (64x128).

#define TB 2
#define TT 2048
#define TD 1024
#define TH 16
#define TM (TB * TT) // 4096

#define NEG_BIG (-1e30f)
#define SCALE_LOG2 0.18033688f  // (1/sqrt(64)) * log2(e)
#define FSHIFT 16.0f            // fixed softmax shift (exact; cancels in O/l)
#define BF16_ONE ((short)0x3F80)

typedef __attribute__((ext_vector_type(8))) short short8;
typedef __attribute__((ext_vector_type(4))) float f32x4;
typedef __attribute__((ext_vector_type(16))) float f32x16;
typedef __attribute__((ext_vector_type(4))) unsigned short ushort4v;
typedef __attribute__((ext_vector_type(4))) unsigned int u32x4;

__device__ __forceinline__ short f2bf(float f) {
    __hip_bfloat16 h = __float2bfloat16(f);
    return __builtin_bit_cast(short, h);
}

__device__ __forceinline__ float bf2f(short u) {
    unsigned int x = ((unsigned int)(unsigned short)u) << 16;
    return __builtin_bit_cast(float, x);
}

__device__ __forceinline__ float fast_exp2(float x) {
#if __has_builtin(__builtin_amdgcn_exp2f)
    return __builtin_amdgcn_exp2f(x);
#else
    return exp2f(x);
#endif
}

__device__ __forceinline__ f32x16 zero16() {
    f32x16 v;
    #pragma unroll
    for (int i = 0; i < 16; ++i) v[i] = 0.f;
    return v;
}

// Async global->LDS DMA, 16 B/lane. LDS dest is wave-uniform base + lane*16;
// global src is per-lane (pre-swizzled). Completion counted by vmcnt; the
// compiler's s_waitcnt vmcnt(0) before s_barrier (__syncthreads) drains it.
__device__ __forceinline__ void gload_lds16(const short* g, short* l) {
    __builtin_amdgcn_global_load_lds(
        (const __attribute__((address_space(1))) unsigned int*)g,
        (__attribute__((address_space(3))) unsigned int*)l,
        16, 0, 0);
}

// Inline dtype detect: sample even u16s of x; uniform per wave.
__device__ __forceinline__ int detect_bf16(const unsigned short* xq) {
    int lane = threadIdx.x & 63;
    unsigned short u = xq[lane * 2];
    int e = (u >> 7) & 0xFF;
    int sane = ((e >= 100 && e <= 145) || u == 0) ? 1 : 0;
    unsigned long long b = __ballot(sane);
    return (__popcll(b) >= 48) ? 1 : 0; // 1 = bf16, 0 = fp32
}

// ---------------------------------------------------------------------------
// One dispatch converts x + 4 weights; 8192 elems/block.
// ---------------------------------------------------------------------------
__global__ __launch_bounds__(256) void convert_all_kernel(
    const void* __restrict__ x,  const void* __restrict__ wq,
    const void* __restrict__ wk, const void* __restrict__ wv,
    const void* __restrict__ wo,
    short* __restrict__ xb, short* __restrict__ wqb, short* __restrict__ wkb,
    short* __restrict__ wvb, short* __restrict__ wob)
{
    const int f = detect_bf16((const unsigned short*)x);
    int bid = blockIdx.x;
    const void* src; short* dst; int base;
    if (bid < 512) { src = x; dst = xb; base = bid; }
    else {
        int w = (bid - 512) >> 7, lb = (bid - 512) & 127;
        src = (w == 0) ? wq : (w == 1) ? wk : (w == 2) ? wv : wo;
        dst = (w == 0) ? wqb : (w == 1) ? wkb : (w == 2) ? wvb : wob;
        base = lb;
    }
    int i0 = base * 8192 + (int)threadIdx.x * 8;
    #pragma unroll
    for (int r = 0; r < 4; ++r) {
        int i = i0 + r * 2048;
        if (f) {
            *(short8*)(dst + i) = *(const short8*)((const short*)src + i);
        } else {
            const float* s = (const float*)src + i;
            short8 o;
            #pragma unroll
            for (int j = 0; j < 8; ++j) o[j] = f2bf(s[j]);
            *(short8*)(dst + i) = o;
        }
    }
}

// ---------------------------------------------------------------------------
// GEMM core, global_load_lds staging (m97 structure). C[m,n]=sum_k A[m,k]B[n,k].
// Tile: MROWS x 128, BK=64, K=1024. 4 waves (2x2). XOR chunk swizzle folded
// into the per-lane GLOBAL source address; LDS writes stay linear (lane*16B).
// ---------------------------------------------------------------------------
template<int MROWS>
__device__ __forceinline__ void gemm_core_lds(
    const short* __restrict__ A, const short* __restrict__ B,
    short* SM, int mbase, int nbase, f32x4 (*acc)[4])
{
    constexpr int TA = MROWS / 32;
    short* As = SM;
    short* Bs = SM + MROWS * 64;

    const int tid = threadIdx.x;
    const int wave = tid >> 6, lane = tid & 63;
    const int wm = wave >> 1, wn = wave & 1;
    const int lr = lane & 15;
    const int srow = lane >> 3, jcl = lane & 7;
    const int jc = (jcl ^ srow) * 8;   // (r&7)==srow for all staged rows

    #pragma unroll
    for (int a = 0; a < TA; ++a)
        #pragma unroll
        for (int b = 0; b < 4; ++b) acc[a][b] = (f32x4){0, 0, 0, 0};

    const short* aA[TA]; short* lA[TA];
    const short* aB[4];  short* lB[4];
    #pragma unroll
    for (int t = 0; t < TA; ++t) {
        int w = wave * TA + t;
        aA[t] = A + (size_t)(mbase + w * 8 + srow) * TD + jc;
        lA[t] = As + w * 512;
    }
    #pragma unroll
    for (int t = 0; t < 4; ++t) {
        int w = wave * 4 + t;
        aB[t] = B + (size_t)(nbase + w * 8 + srow) * TD + jc;
        lB[t] = Bs + w * 512;
    }

    // prologue: issue k0=0 tile
    #pragma unroll
    for (int t = 0; t < TA; ++t) gload_lds16(aA[t], lA[t]);
    #pragma unroll
    for (int t = 0; t < 4; ++t)  gload_lds16(aB[t], lB[t]);

    for (int k0 = 0; k0 < TD; k0 += 64) {
        __syncthreads();   // staged loads complete (vmcnt drained per-wave)
        #pragma unroll
        for (int kk = 0; kk < 64; kk += 32) {
            const int cc = (kk >> 3) + (lane >> 4);
            const int csw = (cc ^ (lr & 7)) << 3;
            short8 af[TA], bf[4];
            #pragma unroll
            for (int a = 0; a < TA; ++a)
                af[a] = *(const short8*)&As[(wm * (MROWS / 2) + a * 16 + lr) * 64 + csw];
            #pragma unroll
            for (int b = 0; b < 4; ++b)
                bf[b] = *(const short8*)&Bs[(wn * 64 + b * 16 + lr) * 64 + csw];
            #pragma unroll
            for (int a = 0; a < TA; ++a)
                #pragma unroll
                for (int b = 0; b < 4; ++b)
                    acc[a][b] = __builtin_amdgcn_mfma_f32_16x16x32_bf16(af[a], bf[b], acc[a][b], 0, 0, 0);
        }
        if (k0 + 64 < TD) {
            __syncthreads();   // all LDS reads done; safe to overwrite
            #pragma unroll
            for (int t = 0; t < TA; ++t) gload_lds16(aA[t] + k0 + 64, lA[t]);
            #pragma unroll
            for (int t = 0; t < 4; ++t)  gload_lds16(aB[t] + k0 + 64, lB[t]);
        }
    }
}

// ---------------------------------------------------------------------------
// QKV projection; 128x128 tiles, grid (32, 8, 3).
// Q,K out [B,H,T,64] via LDS-transposed coalesced epilogue; V out [B,H,64,T].
// ---------------------------------------------------------------------------
__global__ __launch_bounds__(256, 3) void qkv_gemm_kernel(
    const short* __restrict__ x,
    const short* __restrict__ Wq, const short* __restrict__ Wk,
    const short* __restrict__ Wv,
    short* __restrict__ Qo, short* __restrict__ Ko, short* __restrict__ Vo)
{
    const short* W = (blockIdx.z == 0) ? Wq : (blockIdx.z == 1) ? Wk : Wv;
    short* Out = (blockIdx.z == 0) ? Qo : (blockIdx.z == 1) ? Ko : Vo;
    const bool transposeV = (blockIdx.z == 2);

    __shared__ __align__(16) short SM[128 * 64 * 2];

    const int mbase = blockIdx.x * 128, nbase = blockIdx.y * 128;
    f32x4 acc[4][4];
    gemm_core_lds<128>(x, W, SM, mbase, nbase, acc);

    const int tid = threadIdx.x;
    const int wave = tid >> 6, lane = tid & 63;
    const int wm = wave >> 1, wn = wave & 1;
    const int lr = lane & 15;
    const int g4 = (lane >> 4) * 4;

    if (transposeV) {
        #pragma unroll
        for (int a = 0; a < 4; ++a) {
            #pragma unroll
            for (int b = 0; b < 4; ++b) {
                int m0 = mbase + wm * 64 + a * 16 + g4;
                int n = nbase + wn * 64 + b * 16 + lr;
                int bb = m0 >> 11, t0 = m0 & (TT - 1);
                int h = n >> 6, hd = n & 63;
                ushort4v pk;
                #pragma unroll
                for (int i = 0; i < 4; ++i) pk[i] = (unsigned short)f2bf(acc[a][b][i]);
                *(ushort4v*)&Out[((size_t)(bb * TH + h) * 64 + hd) * TT + t0] = pk;
            }
        }
    } else {
        short* Cs = SM;
        #pragma unroll
        for (int p = 0; p < 2; ++p) {
            __syncthreads();
            if (wn == p) {
                #pragma unroll
                for (int a = 0; a < 4; ++a)
                    #pragma unroll
                    for (int b = 0; b < 4; ++b)
                        #pragma unroll
                        for (int i = 0; i < 4; ++i) {
                            int ml = wm * 64 + a * 16 + g4 + i;
                            int nl = b * 16 + lr;
                            Cs[ml * 72 + nl] = f2bf(acc[a][b][i]);
                        }
            }
            __syncthreads();
            int tl = tid >> 1, hc = (tid & 1) * 32;
            int h = (nbase >> 6) + p;
            int m = mbase + tl;
            int bb = m >> 11, t = m & (TT - 1);
            size_t base = (((size_t)(bb * TH + h) * TT + t) << 6) + hc;
            #pragma unroll
            for (int q = 0; q < 4; ++q)
                *(short8*)&Out[base + q * 8] = *(short8*)&Cs[tl * 72 + hc + q * 8];
        }
    }
}

// ---------------------------------------------------------------------------
// Output projection; 64x128 tiles, grid (64, 8).
// ---------------------------------------------------------------------------
__global__ __launch_bounds__(256, 3) void out_gemm_kernel(
    const short* __restrict__ A, const short* __restrict__ W,
    void* __restrict__ C, const unsigned short* __restrict__ xq)
{
    const int f = detect_bf16(xq);

    __shared__ __align__(16) short SM[64 * 64 + 128 * 64];

    const int mbase = blockIdx.x * 64, nbase = blockIdx.y * 128;
    f32x4 acc[2][4];
    gemm_core_lds<64>(A, W, SM, mbase, nbase, acc);

    const int tid = threadIdx.x;
    const int wave = tid >> 6, lane = tid & 63;
    const int wm = wave >> 1, wn = wave & 1;
    const int lr = lane & 15;
    const int g4 = (lane >> 4) * 4;

    #pragma unroll
    for (int a = 0; a < 2; ++a) {
        #pragma unroll
        for (int b = 0; b < 4; ++b) {
            #pragma unroll
            for (int i = 0; i < 4; ++i) {
                int m = mbase + wm * 32 + a * 16 + g4 + i;
                int n = nbase + wn * 64 + b * 16 + lr;
                if (f) ((short*)C)[(size_t)m * TD + n] = f2bf(acc[a][b][i]);
                else   ((float*)C)[(size_t)m * TD + n] = acc[a][b][i];
            }
        }
    }
}

// ---------------------------------------------------------------------------
// Split-S flash attention, 32x32 MFMA, swapped QK^T (S^T = K Q^T), softmax
// fully in registers, P->bf16 via v_cvt_pk_bf16_f32 + v_permlane32_swap_b32,
// l on the MFMA pipe via ones-A-frag. 128 q-rows/block (4 waves x 32 q-rows),
// K/V LDS double-buffer, ONE barrier per 64-k tile. grid (32 bh, 32 work).
// setprio(1) around MFMA clusters (T5). 4 blocks/CU (LDS 36.9KB, VGPR<=128).
// ---------------------------------------------------------------------------
__global__ __launch_bounds__(256, 4) void attn_split_kernel(
    const short* __restrict__ Q, const short* __restrict__ K,
    const short* __restrict__ V, short* __restrict__ Opart,
    float* __restrict__ lbuf)
{
    const int bh = blockIdx.x;
    const int y = blockIdx.y;
    const int qt = 15 - (y >> 1);
    const int half = y & 1;
    const int nt0 = qt + 1;
    const int tb = half ? nt0 : 0;
    const int te = half ? (2 * qt + 2) : nt0;

    const int qbase = qt * 128;
    const short* Qp = Q + (size_t)bh * TT * 64;
    const short* Kp = K + (size_t)bh * TT * 64;
    const short* Vp = V + (size_t)bh * 64 * TT;   // V^T: [64][TT]

    __shared__ __align__(16) short SMEM[18432];   // Ks[2][64][72] | Vt[2][64][72]
    short (*Ks)[64][72] = (short (*)[64][72])(SMEM);
    short (*Vt)[64][72] = (short (*)[64][72])(SMEM + 9216);

    const int tid = threadIdx.x;
    const int wave = tid >> 6, lane = tid & 63;
    const int l31 = lane & 31, g = lane >> 5;

    const size_t pslot = (size_t)((half * 32 + bh) * 16 + qt);
    float* lrow = lbuf + pslot * 128;
    short* Ob = Opart + pslot * 8192;

    // staging coords: each thread stages 2 K rows + 2 V rows, 16B each
    const int r0 = tid >> 3, c0 = (tid & 7) * 8;
    const int r1 = r0 + 32;

    // Q fragments (B-operand): lane holds q-row qrow, 64 hd in 4 chunks
    const int qrow0 = qbase + wave * 32;      // wave's min q (uniform)
    const int qrow = qrow0 + l31;             // this lane's q row
    short8 qf[4];
    #pragma unroll
    for (int c = 0; c < 4; ++c)
        qf[c] = *(const short8*)&Qp[(size_t)qrow * 64 + c * 16 + g * 8];

    short8 ones8;
    #pragma unroll
    for (int i = 0; i < 8; ++i) ones8[i] = BF16_ONE;

    f32x16 Oa[2];                // O^T accum: [hd-tile][ (hd-row, q) frag ]
    Oa[0] = zero16(); Oa[1] = zero16();
    f32x16 La = zero16();        // l (all 32 rows identical = l[q])

    // prologue: stage first tile into buf 0
    {
        const int kb = tb * 64;
        *(short8*)&Ks[0][r0][c0] = *(const short8*)&Kp[(size_t)(kb + r0) * 64 + c0];
        *(short8*)&Ks[0][r1][c0] = *(const short8*)&Kp[(size_t)(kb + r1) * 64 + c0];
        *(short8*)&Vt[0][r0][c0] = *(const short8*)&Vp[(size_t)r0 * TT + kb + c0];
        *(short8*)&Vt[0][r1][c0] = *(const short8*)&Vp[(size_t)r1 * TT + kb + c0];
    }
    __syncthreads();

    int buf = 0;
    for (int it = tb; it < te; ++it) {
        const int kt = it * 64;
        const bool more = (it + 1) < te;
        short8 ka, kb2, va, vb;
        if (more) {
            const int kn = kt + 64;
            ka  = *(const short8*)&Kp[(size_t)(kn + r0) * 64 + c0];
            kb2 = *(const short8*)&Kp[(size_t)(kn + r1) * 64 + c0];
            va  = *(const short8*)&Vp[(size_t)r0 * TT + kn + c0];
            vb  = *(const short8*)&Vp[(size_t)r1 * TT + kn + c0];
        }

        #pragma unroll
        for (int t = 0; t < 2; ++t) {
            const int kb32 = kt + t * 32;
            if (kb32 > qrow0 + 31) continue;   // fully masked (wave-uniform)

            // S^T subtile = K(32 k-rows) . Q^T, accumulate over hd
            f32x16 S = zero16();
            __builtin_amdgcn_s_setprio(1);
            #pragma unroll
            for (int c = 0; c < 4; ++c) {
                short8 kf = *(const short8*)&Ks[buf][t * 32 + l31][c * 16 + g * 8];
                S = __builtin_amdgcn_mfma_f32_32x32x16_bf16(kf, qf[c], S, 0, 0, 0);
            }
            __builtin_amdgcn_s_setprio(0);

            // P = 2^(S*scale - 16) IN PLACE (caps transient VGPR at 16);
            // causal mask -> 0 (exact fixed-shift)
            const bool partm = (kb32 + 31) > qrow0;
            if (partm) {
                #pragma unroll
                for (int r = 0; r < 16; ++r) {
                    int kglob = kb32 + (r & 3) + ((r >> 2) << 3) + 4 * g;
                    float arg = S[r] * SCALE_LOG2 - FSHIFT;
                    S[r] = fast_exp2(kglob > qrow ? NEG_BIG : arg);
                }
            } else {
                #pragma unroll
                for (int r = 0; r < 16; ++r)
                    S[r] = fast_exp2(S[r] * SCALE_LOG2 - FSHIFT);
            }

            // pack to bf16 B-fragments in-register (T12):
            // word(c2,j): lane-half g holds k-pair {16c2+8g+2j, +1}
            unsigned int w[8];
            #pragma unroll
            for (int j = 0; j < 2; ++j) {
                unsigned int a, b;
                asm("v_cvt_pk_bf16_f32 %0, %1, %2" : "=v"(a) : "v"(S[2 * j]), "v"(S[2 * j + 1]));
                asm("v_cvt_pk_bf16_f32 %0, %1, %2" : "=v"(b) : "v"(S[2 * j + 4]), "v"(S[2 * j + 5]));
                asm("v_permlane32_swap_b32 %0, %1" : "+v"(a), "+v"(b));
                w[j] = a; w[j + 2] = b;
                unsigned int a2, b2;
                asm("v_cvt_pk_bf16_f32 %0, %1, %2" : "=v"(a2) : "v"(S[8 + 2 * j]), "v"(S[9 + 2 * j]));
                asm("v_cvt_pk_bf16_f32 %0, %1, %2" : "=v"(b2) : "v"(S[12 + 2 * j]), "v"(S[13 + 2 * j]));
                asm("v_permlane32_swap_b32 %0, %1" : "+v"(a2), "+v"(b2));
                w[4 + j] = a2; w[6 + j] = b2;
            }
            u32x4 u0 = {w[0], w[1], w[2], w[3]};
            u32x4 u1 = {w[4], w[5], w[6], w[7]};
            short8 pf0 = __builtin_bit_cast(short8, u0);  // k [kb32, kb32+16)
            short8 pf1 = __builtin_bit_cast(short8, u1);  // k [kb32+16, +32)

            // O^T += V^T . P ; L += ones . P (row sums on matrix pipe)
            __builtin_amdgcn_s_setprio(1);
            #pragma unroll
            for (int h = 0; h < 2; ++h) {
                short8 vf0 = *(const short8*)&Vt[buf][h * 32 + l31][(2 * t) * 16 + g * 8];
                Oa[h] = __builtin_amdgcn_mfma_f32_32x32x16_bf16(vf0, pf0, Oa[h], 0, 0, 0);
                short8 vf1 = *(const short8*)&Vt[buf][h * 32 + l31][(2 * t + 1) * 16 + g * 8];
                Oa[h] = __builtin_amdgcn_mfma_f32_32x32x16_bf16(vf1, pf1, Oa[h], 0, 0, 0);
            }
            La = __builtin_amdgcn_mfma_f32_32x32x16_bf16(ones8, pf0, La, 0, 0, 0);
            La = __builtin_amdgcn_mfma_f32_32x32x16_bf16(ones8, pf1, La, 0, 0, 0);
            __builtin_amdgcn_s_setprio(0);
        }

        // stage next tile into the alternate buffer, then ONE barrier
        if (more) {
            *(short8*)&Ks[buf ^ 1][r0][c0] = ka;
            *(short8*)&Ks[buf ^ 1][r1][c0] = kb2;
            *(short8*)&Vt[buf ^ 1][r0][c0] = va;
            *(short8*)&Vt[buf ^ 1][r1][c0] = vb;
        }
        __syncthreads();
        buf ^= 1;
    }

    // epilogue: O^T (regs) -> LDS f32 -> transposed coalesced bf16 store.
    // Reuse Ks/Vt region (all compute done; last barrier passed).
    float* OT = (float*)SMEM;    // [64][132] f32 = 33792 B <= 36864 B
    #pragma unroll
    for (int h = 0; h < 2; ++h)
        #pragma unroll
        for (int r = 0; r < 16; ++r) {
            int hd = h * 32 + (r & 3) + ((r >> 2) << 3) + 4 * g;
            OT[hd * 132 + wave * 32 + l31] = Oa[h][r];
        }
    if (lane < 32) lrow[wave * 32 + l31] = La[0];
    __syncthreads();
    {
        const int q = tid >> 1, hc = (tid & 1) * 32;
        short tmp[32];
        #pragma unroll
        for (int i = 0; i < 32; ++i)
            tmp[i] = f2bf(OT[(hc + i) * 132 + q]);
        #pragma unroll
        for (int v = 0; v < 4; ++v)
            *(short8*)&Ob[q * 64 + hc + v * 8] = *(short8*)&tmp[v * 8];
    }
}

// ---------------------------------------------------------------------------
// Merge: O = (O0 + O1) / (l0 + l1). grid (32 bh, 16 qt), 256 threads.
// Opart slots are [128 q][64 hd] bf16; element-wise, fully coalesced.
// ---------------------------------------------------------------------------
__global__ __launch_bounds__(256) void attn_merge_kernel(
    const short* __restrict__ Opart, const float* __restrict__ lbuf,
    short* __restrict__ AO)
{
    const int bh = blockIdx.x, qt = blockIdx.y;
    const int b = bh >> 4, h = bh & 15;
    const int t = threadIdx.x;
    const int r = t >> 1, hc = (t & 1) * 32;

    const size_t s0 = (size_t)bh * 16 + qt;
    const size_t s1 = (size_t)(32 + bh) * 16 + qt;
    const float inv = 1.0f / (lbuf[s0 * 128 + r] + lbuf[s1 * 128 + r]);

    const size_t o0 = s0 * 8192 + (size_t)r * 64 + hc;
    const size_t o1 = s1 * 8192 + (size_t)r * 64 + hc;
    size_t ab = ((size_t)(b * TT + qt * 128 + r) << 10) + h * 64 + hc;
    #pragma unroll
    for (int v = 0; v < 4; ++v) {
        short8 va = *(const short8*)&Opart[o0 + v * 8];
        short8 vb = *(const short8*)&Opart[o1 + v * 8];
        short8 ov;
        #pragma unroll
        for (int i = 0; i < 8; ++i)
            ov[i] = f2bf((bf2f(va[i]) + bf2f(vb[i])) * inv);
        *(short8*)&AO[ab + v * 8] = ov;
    }
}

// ---------------------------------------------------------------------------
// Fallback single-pass attention (fixed-shift + ones-row l) for small ws.
// ---------------------------------------------------------------------------
__global__ __launch_bounds__(256) void attn_kernel(
    const short* __restrict__ Q, const short* __restrict__ K,
    const short* __restrict__ V, short* __restrict__ AO)
{
    const int j = blockIdx.y, cdeal = j & 7, rdeal = j >> 3;
    const int qtile = (rdeal == 0) ? 31 - cdeal :
                      (rdeal == 1) ? 16 + cdeal :
                      (rdeal == 2) ? 15 - cdeal : cdeal;
    const int bh = blockIdx.x;
    const int qbase = qtile * 64;
    const short* Qp = Q + (size_t)bh * TT * 64;
    const short* Kp = K + (size_t)bh * TT * 64;
    const short* Vp = V + (size_t)bh * 64 * TT;

    __shared__ __align__(16) short Ks[64][72];
    __shared__ __align__(16) short Vt[64][72];
    __shared__ __align__(16) short Ps[4][16][72];

    const int tid = threadIdx.x;
    const int wave = tid >> 6, lane = tid & 63;
    const int lr = lane & 15;
    const int lk = (lane >> 4) * 8;
    const int g4 = (lane >> 4) * 4;
    const int b = bh >> 4, h = bh & 15;

    const int r0 = tid >> 3, c0 = (tid & 7) * 8;
    const int r1 = (tid + 256) >> 3, c1 = c0;

    const int qrowA = qbase + wave * 16 + lr;
    const short8 qf0 = *(const short8*)&Qp[(size_t)qrowA * 64 + lk];
    const short8 qf1 = *(const short8*)&Qp[(size_t)qrowA * 64 + 32 + lk];

    short8 ones8;
    #pragma unroll
    for (int i = 0; i < 8; ++i) ones8[i] = BF16_ONE;

    f32x4 Oa[4] = {{0,0,0,0},{0,0,0,0},{0,0,0,0},{0,0,0,0}};
    f32x4 La = {0, 0, 0, 0};

    {
        *(short8*)&Ks[r0][c0] = *(const short8*)&Kp[(size_t)r0 * 64 + c0];
        *(short8*)&Ks[r1][c1] = *(const short8*)&Kp[(size_t)r1 * 64 + c1];
        *(short8*)&Vt[r0][c0] = *(const short8*)&Vp[(size_t)r0 * TT + c0];
        *(short8*)&Vt[r1][c1] = *(const short8*)&Vp[(size_t)r1 * TT + c1];
    }
    __syncthreads();

    const int kend = qbase + 64;
    for (int kt = 0; kt < kend; kt += 64) {
        const bool more = (kt + 64) < kend;
        short8 ka, kb, va, vb;
        if (more) {
            const int kn = kt + 64;
            ka = *(const short8*)&Kp[(size_t)(kn + r0) * 64 + c0];
            kb = *(const short8*)&Kp[(size_t)(kn + r1) * 64 + c1];
            va = *(const short8*)&Vp[(size_t)r0 * TT + kn + c0];
            vb = *(const short8*)&Vp[(size_t)r1 * TT + kn + c1];
        }

        f32x4 s[4];
        #pragma unroll
        for (int c = 0; c < 4; ++c) {
            f32x4 z = {0, 0, 0, 0};
            short8 k0v = *(const short8*)&Ks[c * 16 + lr][lk];
            short8 k1v = *(const short8*)&Ks[c * 16 + lr][32 + lk];
            z = __builtin_amdgcn_mfma_f32_16x16x32_bf16(k0v, qf0, z, 0, 0, 0);
            z = __builtin_amdgcn_mfma_f32_16x16x32_bf16(k1v, qf1, z, 0, 0, 0);
            s[c] = z;
        }

        const bool diag = (kt == qbase);
        #pragma unroll
        for (int c = 0; c < 4; ++c) {
            ushort4v pk;
            #pragma unroll
            for (int i = 0; i < 4; ++i) {
                float arg = s[c][i] * SCALE_LOG2 - FSHIFT;
                if (diag) {
                    int colg = kt + c * 16 + g4 + i;
                    if (colg > qrowA) arg = NEG_BIG;
                }
                pk[i] = (unsigned short)f2bf(fast_exp2(arg));
            }
            *(ushort4v*)&Ps[wave][lr][c * 16 + g4] = pk;
        }

        #pragma unroll
        for (int kk = 0; kk < 2; ++kk) {
            short8 af = *(const short8*)&Ps[wave][lr][kk * 32 + lk];
            #pragma unroll
            for (int c = 0; c < 4; ++c) {
                short8 bf = *(const short8*)&Vt[c * 16 + lr][kk * 32 + lk];
                Oa[c] = __builtin_amdgcn_mfma_f32_16x16x32_bf16(af, bf, Oa[c], 0, 0, 0);
            }
            La = __builtin_amdgcn_mfma_f32_16x16x32_bf16(af, ones8, La, 0, 0, 0);
        }
        __syncthreads();

        if (more) {
            *(short8*)&Ks[r0][c0] = ka;
            *(short8*)&Ks[r1][c1] = kb;
            *(short8*)&Vt[r0][c0] = va;
            *(short8*)&Vt[r1][c1] = vb;
            __syncthreads();
        }
    }

    #pragma unroll
    for (int c = 0; c < 4; ++c) {
        #pragma unroll
        for (int i = 0; i < 4; ++i) {
            int qr = qbase + wave * 16 + g4 + i;
            float v = Oa[c][i] / La[i];
            AO[((size_t)(b * TT + qr) << 10) + h * 64 + c * 16 + lr] = f2bf(v);
        }
    }
}

// ---------------------------------------------------------------------------
extern "C" void kernel_launch(void* const* d_in, const int* in_sizes, int n_in,
                              void* d_out, int out_size, void* d_ws, size_t ws_size,
                              hipStream_t stream)
{
    char* ws = (char*)d_ws;
    const size_t XB  = (size_t)TM * TD * 2;   // 8 MiB bf16 x
    const size_t WB  = (size_t)TD * TD * 2;   // 2 MiB bf16 weight
    const size_t BUF = (size_t)TM * TD * 2;   // 8 MiB activation

    short* xb  = (short*)(ws + 256);
    short* Wqb = (short*)(ws + 256 + XB);
    short* Wkb = (short*)(ws + 256 + XB + WB);
    short* Wvb = (short*)(ws + 256 + XB + 2 * WB);
    short* Wob = (short*)(ws + 256 + XB + 3 * WB);
    char*  act = ws + 256 + XB + 4 * WB;
    short* Qb = (short*)(act);
    short* Kb = (short*)(act + BUF);
    short* Vb = (short*)(act + 2 * BUF);   // V^T [B,H,64,T]
    short* Ab = (short*)(act + 3 * BUF);
    char*  part = act + 4 * BUF;
    short* Opart = (short*)part;                               // 16 MiB
    float* lbuf  = (float*)(part + (size_t)16 * 1024 * 1024);  // 512 KiB

    const size_t need = 256 + XB + 4 * WB + 4 * BUF +
                        (size_t)16 * 1024 * 1024 + 524288;
    const bool splitS = (ws_size >= need);   // constant across calls: graph-safe

    dim3 blk(256);
    convert_all_kernel<<<dim3(512 + 4 * 128), blk, 0, stream>>>(
        d_in[0], d_in[1], d_in[2], d_in[3], d_in[4], xb, Wqb, Wkb, Wvb, Wob);
    qkv_gemm_kernel<<<dim3(TM / 128, TD / 128, 3), blk, 0, stream>>>(xb, Wqb, Wkb, Wvb, Qb, Kb, Vb);
    if (splitS) {
        attn_split_kernel<<<dim3(32, 32), blk, 0, stream>>>(Qb, Kb, Vb, Opart, lbuf);
        attn_merge_kernel<<<dim3(32, 16), blk, 0, stream>>>(Opart, lbuf, Ab);
    } else {
        attn_kernel<<<dim3(32, 32), blk, 0, stream>>>(Qb, Kb, Vb, Ab);
    }
    out_gemm_kernel<<<dim3(TM / 64, TD / 128), blk, 0, stream>>>(
        Ab, Wob, d_out, (const unsigned short*)d_in[0]);
}

// Round 4
// 176.399 us; speedup vs baseline: 1.0490x; 1.0024x over previous
//
#include <hip/hip_runtime.h>
#include <hip/hip_bf16.h>

// Problem: B=2, T=2048, D=1024, H=16, HD=64.
// Runtime-detect fp32 vs bf16 inputs (inline, per-wave); canonicalize to bf16.
// convert_all -> qkv gemm (128x128, global_load_lds staging m97-style;
// Q,K:[B,H,T,64] via LDS-transpose epilogue; V:[B,H,64,T]) -> split-S flash
// attention (32x32 MFMA, swapped QK^T, in-register softmax via cvt_pk_bf16 +
// permlane32_swap, fixed-shift softmax, K/V gload_lds double-buffer w/ XOR
// chunk swizzle, 1 barrier/tile, subtile-pipelined QK/SM/PV phases, MFMA
// ones-row l, setprio) -> merge -> out gemm (64x128).

#define TB 2
#define TT 2048
#define TD 1024
#define TH 16
#define TM (TB * TT) // 4096

#define NEG_BIG (-1e30f)
#define SCALE_LOG2 0.18033688f  // (1/sqrt(64)) * log2(e)
#define FSHIFT 16.0f            // fixed softmax shift (exact; cancels in O/l)
#define BF16_ONE ((short)0x3F80)

typedef __attribute__((ext_vector_type(8))) short short8;
typedef __attribute__((ext_vector_type(4))) float f32x4;
typedef __attribute__((ext_vector_type(16))) float f32x16;
typedef __attribute__((ext_vector_type(4))) unsigned short ushort4v;
typedef __attribute__((ext_vector_type(4))) unsigned int u32x4;

__device__ __forceinline__ short f2bf(float f) {
    __hip_bfloat16 h = __float2bfloat16(f);
    return __builtin_bit_cast(short, h);
}

__device__ __forceinline__ float bf2f(short u) {
    unsigned int x = ((unsigned int)(unsigned short)u) << 16;
    return __builtin_bit_cast(float, x);
}

__device__ __forceinline__ float fast_exp2(float x) {
#if __has_builtin(__builtin_amdgcn_exp2f)
    return __builtin_amdgcn_exp2f(x);
#else
    return exp2f(x);
#endif
}

__device__ __forceinline__ f32x16 zero16() {
    f32x16 v;
    #pragma unroll
    for (int i = 0; i < 16; ++i) v[i] = 0.f;
    return v;
}

// Async global->LDS DMA, 16 B/lane. LDS dest is wave-uniform base + lane*16;
// global src is per-lane (pre-swizzled). Completion counted by vmcnt; the
// compiler's s_waitcnt vmcnt(0) before s_barrier (__syncthreads) drains it.
__device__ __forceinline__ void gload_lds16(const short* g, short* l) {
    __builtin_amdgcn_global_load_lds(
        (const __attribute__((address_space(1))) unsigned int*)g,
        (__attribute__((address_space(3))) unsigned int*)l,
        16, 0, 0);
}

// Inline dtype detect: sample even u16s of x; uniform per wave.
__device__ __forceinline__ int detect_bf16(const unsigned short* xq) {
    int lane = threadIdx.x & 63;
    unsigned short u = xq[lane * 2];
    int e = (u >> 7) & 0xFF;
    int sane = ((e >= 100 && e <= 145) || u == 0) ? 1 : 0;
    unsigned long long b = __ballot(sane);
    return (__popcll(b) >= 48) ? 1 : 0; // 1 = bf16, 0 = fp32
}

// ---------------------------------------------------------------------------
// One dispatch converts x + 4 weights; 8192 elems/block.
// ---------------------------------------------------------------------------
__global__ __launch_bounds__(256) void convert_all_kernel(
    const void* __restrict__ x,  const void* __restrict__ wq,
    const void* __restrict__ wk, const void* __restrict__ wv,
    const void* __restrict__ wo,
    short* __restrict__ xb, short* __restrict__ wqb, short* __restrict__ wkb,
    short* __restrict__ wvb, short* __restrict__ wob)
{
    const int f = detect_bf16((const unsigned short*)x);
    int bid = blockIdx.x;
    const void* src; short* dst; int base;
    if (bid < 512) { src = x; dst = xb; base = bid; }
    else {
        int w = (bid - 512) >> 7, lb = (bid - 512) & 127;
        src = (w == 0) ? wq : (w == 1) ? wk : (w == 2) ? wv : wo;
        dst = (w == 0) ? wqb : (w == 1) ? wkb : (w == 2) ? wvb : wob;
        base = lb;
    }
    int i0 = base * 8192 + (int)threadIdx.x * 8;
    #pragma unroll
    for (int r = 0; r < 4; ++r) {
        int i = i0 + r * 2048;
        if (f) {
            *(short8*)(dst + i) = *(const short8*)((const short*)src + i);
        } else {
            const float* s = (const float*)src + i;
            short8 o;
            #pragma unroll
            for (int j = 0; j < 8; ++j) o[j] = f2bf(s[j]);
            *(short8*)(dst + i) = o;
        }
    }
}

// ---------------------------------------------------------------------------
// GEMM core, global_load_lds staging (m97 structure). C[m,n]=sum_k A[m,k]B[n,k].
// Tile: MROWS x 128, BK=64, K=1024. 4 waves (2x2). XOR chunk swizzle folded
// into the per-lane GLOBAL source address; LDS writes stay linear (lane*16B).
// ---------------------------------------------------------------------------
template<int MROWS>
__device__ __forceinline__ void gemm_core_lds(
    const short* __restrict__ A, const short* __restrict__ B,
    short* SM, int mbase, int nbase, f32x4 (*acc)[4])
{
    constexpr int TA = MROWS / 32;
    short* As = SM;
    short* Bs = SM + MROWS * 64;

    const int tid = threadIdx.x;
    const int wave = tid >> 6, lane = tid & 63;
    const int wm = wave >> 1, wn = wave & 1;
    const int lr = lane & 15;
    const int srow = lane >> 3, jcl = lane & 7;
    const int jc = (jcl ^ srow) * 8;   // (r&7)==srow for all staged rows

    #pragma unroll
    for (int a = 0; a < TA; ++a)
        #pragma unroll
        for (int b = 0; b < 4; ++b) acc[a][b] = (f32x4){0, 0, 0, 0};

    const short* aA[TA]; short* lA[TA];
    const short* aB[4];  short* lB[4];
    #pragma unroll
    for (int t = 0; t < TA; ++t) {
        int w = wave * TA + t;
        aA[t] = A + (size_t)(mbase + w * 8 + srow) * TD + jc;
        lA[t] = As + w * 512;
    }
    #pragma unroll
    for (int t = 0; t < 4; ++t) {
        int w = wave * 4 + t;
        aB[t] = B + (size_t)(nbase + w * 8 + srow) * TD + jc;
        lB[t] = Bs + w * 512;
    }

    // prologue: issue k0=0 tile
    #pragma unroll
    for (int t = 0; t < TA; ++t) gload_lds16(aA[t], lA[t]);
    #pragma unroll
    for (int t = 0; t < 4; ++t)  gload_lds16(aB[t], lB[t]);

    for (int k0 = 0; k0 < TD; k0 += 64) {
        __syncthreads();   // staged loads complete (vmcnt drained per-wave)
        #pragma unroll
        for (int kk = 0; kk < 64; kk += 32) {
            const int cc = (kk >> 3) + (lane >> 4);
            const int csw = (cc ^ (lr & 7)) << 3;
            short8 af[TA], bf[4];
            #pragma unroll
            for (int a = 0; a < TA; ++a)
                af[a] = *(const short8*)&As[(wm * (MROWS / 2) + a * 16 + lr) * 64 + csw];
            #pragma unroll
            for (int b = 0; b < 4; ++b)
                bf[b] = *(const short8*)&Bs[(wn * 64 + b * 16 + lr) * 64 + csw];
            #pragma unroll
            for (int a = 0; a < TA; ++a)
                #pragma unroll
                for (int b = 0; b < 4; ++b)
                    acc[a][b] = __builtin_amdgcn_mfma_f32_16x16x32_bf16(af[a], bf[b], acc[a][b], 0, 0, 0);
        }
        if (k0 + 64 < TD) {
            __syncthreads();   // all LDS reads done; safe to overwrite
            #pragma unroll
            for (int t = 0; t < TA; ++t) gload_lds16(aA[t] + k0 + 64, lA[t]);
            #pragma unroll
            for (int t = 0; t < 4; ++t)  gload_lds16(aB[t] + k0 + 64, lB[t]);
        }
    }
}

// ---------------------------------------------------------------------------
// QKV projection; 128x128 tiles, grid (32, 8, 3).
// Q,K out [B,H,T,64] via LDS-transposed coalesced epilogue; V out [B,H,64,T].
// ---------------------------------------------------------------------------
__global__ __launch_bounds__(256, 3) void qkv_gemm_kernel(
    const short* __restrict__ x,
    const short* __restrict__ Wq, const short* __restrict__ Wk,
    const short* __restrict__ Wv,
    short* __restrict__ Qo, short* __restrict__ Ko, short* __restrict__ Vo)
{
    const short* W = (blockIdx.z == 0) ? Wq : (blockIdx.z == 1) ? Wk : Wv;
    short* Out = (blockIdx.z == 0) ? Qo : (blockIdx.z == 1) ? Ko : Vo;
    const bool transposeV = (blockIdx.z == 2);

    __shared__ __align__(16) short SM[128 * 64 * 2];

    const int mbase = blockIdx.x * 128, nbase = blockIdx.y * 128;
    f32x4 acc[4][4];
    gemm_core_lds<128>(x, W, SM, mbase, nbase, acc);

    const int tid = threadIdx.x;
    const int wave = tid >> 6, lane = tid & 63;
    const int wm = wave >> 1, wn = wave & 1;
    const int lr = lane & 15;
    const int g4 = (lane >> 4) * 4;

    if (transposeV) {
        #pragma unroll
        for (int a = 0; a < 4; ++a) {
            #pragma unroll
            for (int b = 0; b < 4; ++b) {
                int m0 = mbase + wm * 64 + a * 16 + g4;
                int n = nbase + wn * 64 + b * 16 + lr;
                int bb = m0 >> 11, t0 = m0 & (TT - 1);
                int h = n >> 6, hd = n & 63;
                ushort4v pk;
                #pragma unroll
                for (int i = 0; i < 4; ++i) pk[i] = (unsigned short)f2bf(acc[a][b][i]);
                *(ushort4v*)&Out[((size_t)(bb * TH + h) * 64 + hd) * TT + t0] = pk;
            }
        }
    } else {
        short* Cs = SM;
        #pragma unroll
        for (int p = 0; p < 2; ++p) {
            __syncthreads();
            if (wn == p) {
                #pragma unroll
                for (int a = 0; a < 4; ++a)
                    #pragma unroll
                    for (int b = 0; b < 4; ++b)
                        #pragma unroll
                        for (int i = 0; i < 4; ++i) {
                            int ml = wm * 64 + a * 16 + g4 + i;
                            int nl = b * 16 + lr;
                            Cs[ml * 72 + nl] = f2bf(acc[a][b][i]);
                        }
            }
            __syncthreads();
            int tl = tid >> 1, hc = (tid & 1) * 32;
            int h = (nbase >> 6) + p;
            int m = mbase + tl;
            int bb = m >> 11, t = m & (TT - 1);
            size_t base = (((size_t)(bb * TH + h) * TT + t) << 6) + hc;
            #pragma unroll
            for (int q = 0; q < 4; ++q)
                *(short8*)&Out[base + q * 8] = *(short8*)&Cs[tl * 72 + hc + q * 8];
        }
    }
}

// ---------------------------------------------------------------------------
// Output projection; 64x128 tiles, grid (64, 8).
// ---------------------------------------------------------------------------
__global__ __launch_bounds__(256, 3) void out_gemm_kernel(
    const short* __restrict__ A, const short* __restrict__ W,
    void* __restrict__ C, const unsigned short* __restrict__ xq)
{
    const int f = detect_bf16(xq);

    __shared__ __align__(16) short SM[64 * 64 + 128 * 64];

    const int mbase = blockIdx.x * 64, nbase = blockIdx.y * 128;
    f32x4 acc[2][4];
    gemm_core_lds<64>(A, W, SM, mbase, nbase, acc);

    const int tid = threadIdx.x;
    const int wave = tid >> 6, lane = tid & 63;
    const int wm = wave >> 1, wn = wave & 1;
    const int lr = lane & 15;
    const int g4 = (lane >> 4) * 4;

    #pragma unroll
    for (int a = 0; a < 2; ++a) {
        #pragma unroll
        for (int b = 0; b < 4; ++b) {
            #pragma unroll
            for (int i = 0; i < 4; ++i) {
                int m = mbase + wm * 32 + a * 16 + g4 + i;
                int n = nbase + wn * 64 + b * 16 + lr;
                if (f) ((short*)C)[(size_t)m * TD + n] = f2bf(acc[a][b][i]);
                else   ((float*)C)[(size_t)m * TD + n] = acc[a][b][i];
            }
        }
    }
}

// ---------------------------------------------------------------------------
// Split-S flash attention, 32x32 MFMA, swapped QK^T (S^T = K Q^T), softmax
// fully in registers, P->bf16 via v_cvt_pk_bf16_f32 + v_permlane32_swap_b32,
// l on the MFMA pipe via ones-A-frag. 128 q-rows/block (4 waves x 32 q-rows).
// K/V staged via global_load_lds into [2][64][64] linear LDS with XOR chunk
// swizzle on BOTH sides (rule #21); dbuf, staging issued at loop TOP so DMA
// overlaps the whole tile compute; ONE barrier per 64-k tile. Subtile phases
// pipelined: QK0,QK1 -> SM0,SM1 -> PV0,PV1. grid (32 bh, 32 work).
// ---------------------------------------------------------------------------
__global__ __launch_bounds__(256, 3) void attn_split_kernel(
    const short* __restrict__ Q, const short* __restrict__ K,
    const short* __restrict__ V, short* __restrict__ Opart,
    float* __restrict__ lbuf)
{
    const int bh = blockIdx.x;
    const int y = blockIdx.y;
    const int qt = 15 - (y >> 1);
    const int half = y & 1;
    const int nt0 = qt + 1;
    const int tb = half ? nt0 : 0;
    const int te = half ? (2 * qt + 2) : nt0;

    const int qbase = qt * 128;
    const short* Qp = Q + (size_t)bh * TT * 64;
    const short* Kp = K + (size_t)bh * TT * 64;
    const short* Vp = V + (size_t)bh * 64 * TT;   // V^T: [64][TT]

    __shared__ __align__(16) short SMEM[18432];   // Ks[2][64][64] | Vt[2][64][64] | (epilogue OT)
    short* KsL = SMEM;           // buf stride 4096 shorts
    short* VtL = SMEM + 8192;

    const int tid = threadIdx.x;
    const int wave = tid >> 6, lane = tid & 63;
    const int l31 = lane & 31, g = lane >> 5;
    const int lsw = (l31 & 7);   // XOR swizzle key for ds_reads (rows t*32+l31, h*32+l31)

    const size_t pslot = (size_t)((half * 32 + bh) * 16 + qt);
    float* lrow = lbuf + pslot * 128;
    short* Ob = Opart + pslot * 8192;

    // staging via gload_lds: round r covers rows r*32 + wave*8 + (lane>>3),
    // chunk lane&7; global source pre-swizzled: chunk ^= row&7; LDS linear.
    const int srow_off = wave * 8 + (lane >> 3);   // 0..31
    const int schunk = lane & 7;

    // Q fragments (B-operand): lane holds q-row qrow, 64 hd in 4 chunks
    const int qrow0 = qbase + wave * 32;      // wave's min q (uniform)
    const int qrow = qrow0 + l31;             // this lane's q row
    short8 qf[4];
    #pragma unroll
    for (int c = 0; c < 4; ++c)
        qf[c] = *(const short8*)&Qp[(size_t)qrow * 64 + c * 16 + g * 8];

    short8 ones8;
    #pragma unroll
    for (int i = 0; i < 8; ++i) ones8[i] = BF16_ONE;

    f32x16 Oa[2];                // O^T accum: [hd-tile][ (hd-row, q) frag ]
    Oa[0] = zero16(); Oa[1] = zero16();
    f32x16 La = zero16();        // l (all 32 rows identical = l[q])

    // prologue: stage first tile into buf 0 (DMA, drained by first barrier)
    {
        const int kb = tb * 64;
        #pragma unroll
        for (int r = 0; r < 2; ++r) {
            int row = r * 32 + srow_off;
            gload_lds16(&Kp[(size_t)(kb + row) * 64 + ((schunk ^ (row & 7)) * 8)],
                        KsL + (r * 32 + wave * 8) * 64);
            gload_lds16(&Vp[(size_t)row * TT + kb + ((schunk ^ (row & 7)) * 8)],
                        VtL + (r * 32 + wave * 8) * 64);
        }
    }
    __syncthreads();

    int buf = 0;
    for (int it = tb; it < te; ++it) {
        const int kt = it * 64;
        const bool more = (it + 1) < te;

        // issue next tile's DMA into the alternate buffer NOW: it flies under
        // this tile's compute; the end-of-tile barrier's vmcnt drain covers it.
        if (more) {
            const int kn = kt + 64;
            const int db = (buf ^ 1) * 4096;
            #pragma unroll
            for (int r = 0; r < 2; ++r) {
                int row = r * 32 + srow_off;
                gload_lds16(&Kp[(size_t)(kn + row) * 64 + ((schunk ^ (row & 7)) * 8)],
                            KsL + db + (r * 32 + wave * 8) * 64);
                gload_lds16(&Vp[(size_t)row * TT + kn + ((schunk ^ (row & 7)) * 8)],
                            VtL + db + (r * 32 + wave * 8) * 64);
            }
        }

        const int bb = buf * 4096;
        const bool act0 = (kt) <= qrow0 + 31;        // subtile k [kt, kt+32)
        const bool act1 = (kt + 32) <= qrow0 + 31;   // subtile k [kt+32, kt+64)

        // ---- phase 1: QK^T for both subtiles (MFMA cluster) ----
        f32x16 S[2];
        __builtin_amdgcn_s_setprio(1);
        if (act0) {
            S[0] = zero16();
            #pragma unroll
            for (int c = 0; c < 4; ++c) {
                short8 kf = *(const short8*)&KsL[bb + (l31) * 64 + (((2 * c + g) ^ lsw) * 8)];
                S[0] = __builtin_amdgcn_mfma_f32_32x32x16_bf16(kf, qf[c], S[0], 0, 0, 0);
            }
        }
        if (act1) {
            S[1] = zero16();
            #pragma unroll
            for (int c = 0; c < 4; ++c) {
                short8 kf = *(const short8*)&KsL[bb + (32 + l31) * 64 + (((2 * c + g) ^ lsw) * 8)];
                S[1] = __builtin_amdgcn_mfma_f32_32x32x16_bf16(kf, qf[c], S[1], 0, 0, 0);
            }
        }
        __builtin_amdgcn_s_setprio(0);

        // ---- phase 2: softmax + bf16 pack for both subtiles (VALU) ----
        short8 pf[2][2];
        #pragma unroll
        for (int t = 0; t < 2; ++t) {
            const bool act = t ? act1 : act0;
            if (!act) continue;
            const int kb32 = kt + t * 32;
            const bool partm = (kb32 + 31) > qrow0;
            if (partm) {
                #pragma unroll
                for (int r = 0; r < 16; ++r) {
                    int kglob = kb32 + (r & 3) + ((r >> 2) << 3) + 4 * g;
                    float arg = S[t][r] * SCALE_LOG2 - FSHIFT;
                    S[t][r] = fast_exp2(kglob > qrow ? NEG_BIG : arg);
                }
            } else {
                #pragma unroll
                for (int r = 0; r < 16; ++r)
                    S[t][r] = fast_exp2(S[t][r] * SCALE_LOG2 - FSHIFT);
            }
            // pack to bf16 B-fragments in-register (T12)
            unsigned int w[8];
            #pragma unroll
            for (int j = 0; j < 2; ++j) {
                unsigned int a, b;
                asm("v_cvt_pk_bf16_f32 %0, %1, %2" : "=v"(a) : "v"(S[t][2 * j]), "v"(S[t][2 * j + 1]));
                asm("v_cvt_pk_bf16_f32 %0, %1, %2" : "=v"(b) : "v"(S[t][2 * j + 4]), "v"(S[t][2 * j + 5]));
                asm("v_permlane32_swap_b32 %0, %1" : "+v"(a), "+v"(b));
                w[j] = a; w[j + 2] = b;
                unsigned int a2, b2;
                asm("v_cvt_pk_bf16_f32 %0, %1, %2" : "=v"(a2) : "v"(S[t][8 + 2 * j]), "v"(S[t][9 + 2 * j]));
                asm("v_cvt_pk_bf16_f32 %0, %1, %2" : "=v"(b2) : "v"(S[t][12 + 2 * j]), "v"(S[t][13 + 2 * j]));
                asm("v_permlane32_swap_b32 %0, %1" : "+v"(a2), "+v"(b2));
                w[4 + j] = a2; w[6 + j] = b2;
            }
            u32x4 u0 = {w[0], w[1], w[2], w[3]};
            u32x4 u1 = {w[4], w[5], w[6], w[7]};
            pf[t][0] = __builtin_bit_cast(short8, u0);  // k [kb32, kb32+16)
            pf[t][1] = __builtin_bit_cast(short8, u1);  // k [kb32+16, +32)
        }

        // ---- phase 3: PV + l for both subtiles (MFMA cluster) ----
        __builtin_amdgcn_s_setprio(1);
        #pragma unroll
        for (int t = 0; t < 2; ++t) {
            const bool act = t ? act1 : act0;
            if (!act) continue;
            #pragma unroll
            for (int h = 0; h < 2; ++h) {
                short8 vf0 = *(const short8*)&VtL[bb + (h * 32 + l31) * 64 + (((4 * t + g) ^ lsw) * 8)];
                Oa[h] = __builtin_amdgcn_mfma_f32_32x32x16_bf16(vf0, pf[t][0], Oa[h], 0, 0, 0);
                short8 vf1 = *(const short8*)&VtL[bb + (h * 32 + l31) * 64 + (((4 * t + 2 + g) ^ lsw) * 8)];
                Oa[h] = __builtin_amdgcn_mfma_f32_32x32x16_bf16(vf1, pf[t][1], Oa[h], 0, 0, 0);
            }
            La = __builtin_amdgcn_mfma_f32_32x32x16_bf16(ones8, pf[t][0], La, 0, 0, 0);
            La = __builtin_amdgcn_mfma_f32_32x32x16_bf16(ones8, pf[t][1], La, 0, 0, 0);
        }
        __builtin_amdgcn_s_setprio(0);

        __syncthreads();   // drains this wave's DMA (vmcnt 0) + all LDS reads
        buf ^= 1;
    }

    // epilogue: O^T (regs) -> LDS f32 -> transposed coalesced bf16 store.
    // Reuse Ks/Vt region (all compute done; last barrier passed).
    float* OT = (float*)SMEM;    // [64][132] f32 = 33792 B <= 36864 B
    #pragma unroll
    for (int h = 0; h < 2; ++h)
        #pragma unroll
        for (int r = 0; r < 16; ++r) {
            int hd = h * 32 + (r & 3) + ((r >> 2) << 3) + 4 * g;
            OT[hd * 132 + wave * 32 + l31] = Oa[h][r];
        }
    if (lane < 32) lrow[wave * 32 + l31] = La[0];
    __syncthreads();
    {
        const int q = tid >> 1, hc = (tid & 1) * 32;
        short tmp[32];
        #pragma unroll
        for (int i = 0; i < 32; ++i)
            tmp[i] = f2bf(OT[(hc + i) * 132 + q]);
        #pragma unroll
        for (int v = 0; v < 4; ++v)
            *(short8*)&Ob[q * 64 + hc + v * 8] = *(short8*)&tmp[v * 8];
    }
}

// ---------------------------------------------------------------------------
// Merge: O = (O0 + O1) / (l0 + l1). grid (32 bh, 16 qt), 256 threads.
// Opart slots are [128 q][64 hd] bf16; element-wise, fully coalesced.
// ---------------------------------------------------------------------------
__global__ __launch_bounds__(256) void attn_merge_kernel(
    const short* __restrict__ Opart, const float* __restrict__ lbuf,
    short* __restrict__ AO)
{
    const int bh = blockIdx.x, qt = blockIdx.y;
    const int b = bh >> 4, h = bh & 15;
    const int t = threadIdx.x;
    const int r = t >> 1, hc = (t & 1) * 32;

    const size_t s0 = (size_t)bh * 16 + qt;
    const size_t s1 = (size_t)(32 + bh) * 16 + qt;
    const float inv = 1.0f / (lbuf[s0 * 128 + r] + lbuf[s1 * 128 + r]);

    const size_t o0 = s0 * 8192 + (size_t)r * 64 + hc;
    const size_t o1 = s1 * 8192 + (size_t)r * 64 + hc;
    size_t ab = ((size_t)(b * TT + qt * 128 + r) << 10) + h * 64 + hc;
    #pragma unroll
    for (int v = 0; v < 4; ++v) {
        short8 va = *(const short8*)&Opart[o0 + v * 8];
        short8 vb = *(const short8*)&Opart[o1 + v * 8];
        short8 ov;
        #pragma unroll
        for (int i = 0; i < 8; ++i)
            ov[i] = f2bf((bf2f(va[i]) + bf2f(vb[i])) * inv);
        *(short8*)&AO[ab + v * 8] = ov;
    }
}

// ---------------------------------------------------------------------------
// Fallback single-pass attention (fixed-shift + ones-row l) for small ws.
// ---------------------------------------------------------------------------
__global__ __launch_bounds__(256) void attn_kernel(
    const short* __restrict__ Q, const short* __restrict__ K,
    const short* __restrict__ V, short* __restrict__ AO)
{
    const int j = blockIdx.y, cdeal = j & 7, rdeal = j >> 3;
    const int qtile = (rdeal == 0) ? 31 - cdeal :
                      (rdeal == 1) ? 16 + cdeal :
                      (rdeal == 2) ? 15 - cdeal : cdeal;
    const int bh = blockIdx.x;
    const int qbase = qtile * 64;
    const short* Qp = Q + (size_t)bh * TT * 64;
    const short* Kp = K + (size_t)bh * TT * 64;
    const short* Vp = V + (size_t)bh * 64 * TT;

    __shared__ __align__(16) short Ks[64][72];
    __shared__ __align__(16) short Vt[64][72];
    __shared__ __align__(16) short Ps[4][16][72];

    const int tid = threadIdx.x;
    const int wave = tid >> 6, lane = tid & 63;
    const int lr = lane & 15;
    const int lk = (lane >> 4) * 8;
    const int g4 = (lane >> 4) * 4;
    const int b = bh >> 4, h = bh & 15;

    const int r0 = tid >> 3, c0 = (tid & 7) * 8;
    const int r1 = (tid + 256) >> 3, c1 = c0;

    const int qrowA = qbase + wave * 16 + lr;
    const short8 qf0 = *(const short8*)&Qp[(size_t)qrowA * 64 + lk];
    const short8 qf1 = *(const short8*)&Qp[(size_t)qrowA * 64 + 32 + lk];

    short8 ones8;
    #pragma unroll
    for (int i = 0; i < 8; ++i) ones8[i] = BF16_ONE;

    f32x4 Oa[4] = {{0,0,0,0},{0,0,0,0},{0,0,0,0},{0,0,0,0}};
    f32x4 La = {0, 0, 0, 0};

    {
        *(short8*)&Ks[r0][c0] = *(const short8*)&Kp[(size_t)r0 * 64 + c0];
        *(short8*)&Ks[r1][c1] = *(const short8*)&Kp[(size_t)r1 * 64 + c1];
        *(short8*)&Vt[r0][c0] = *(const short8*)&Vp[(size_t)r0 * TT + c0];
        *(short8*)&Vt[r1][c1] = *(const short8*)&Vp[(size_t)r1 * TT + c1];
    }
    __syncthreads();

    const int kend = qbase + 64;
    for (int kt = 0; kt < kend; kt += 64) {
        const bool more = (kt + 64) < kend;
        short8 ka, kb, va, vb;
        if (more) {
            const int kn = kt + 64;
            ka = *(const short8*)&Kp[(size_t)(kn + r0) * 64 + c0];
            kb = *(const short8*)&Kp[(size_t)(kn + r1) * 64 + c1];
            va = *(const short8*)&Vp[(size_t)r0 * TT + kn + c0];
            vb = *(const short8*)&Vp[(size_t)r1 * TT + kn + c1];
        }

        f32x4 s[4];
        #pragma unroll
        for (int c = 0; c < 4; ++c) {
            f32x4 z = {0, 0, 0, 0};
            short8 k0v = *(const short8*)&Ks[c * 16 + lr][lk];
            short8 k1v = *(const short8*)&Ks[c * 16 + lr][32 + lk];
            z = __builtin_amdgcn_mfma_f32_16x16x32_bf16(k0v, qf0, z, 0, 0, 0);
            z = __builtin_amdgcn_mfma_f32_16x16x32_bf16(k1v, qf1, z, 0, 0, 0);
            s[c] = z;
        }

        const bool diag = (kt == qbase);
        #pragma unroll
        for (int c = 0; c < 4; ++c) {
            ushort4v pk;
            #pragma unroll
            for (int i = 0; i < 4; ++i) {
                float arg = s[c][i] * SCALE_LOG2 - FSHIFT;
                if (diag) {
                    int colg = kt + c * 16 + g4 + i;
                    if (colg > qrowA) arg = NEG_BIG;
                }
                pk[i] = (unsigned short)f2bf(fast_exp2(arg));
            }
            *(ushort4v*)&Ps[wave][lr][c * 16 + g4] = pk;
        }

        #pragma unroll
        for (int kk = 0; kk < 2; ++kk) {
            short8 af = *(const short8*)&Ps[wave][lr][kk * 32 + lk];
            #pragma unroll
            for (int c = 0; c < 4; ++c) {
                short8 bf = *(const short8*)&Vt[c * 16 + lr][kk * 32 + lk];
                Oa[c] = __builtin_amdgcn_mfma_f32_16x16x32_bf16(af, bf, Oa[c], 0, 0, 0);
            }
            La = __builtin_amdgcn_mfma_f32_16x16x32_bf16(af, ones8, La, 0, 0, 0);
        }
        __syncthreads();

        if (more) {
            *(short8*)&Ks[r0][c0] = ka;
            *(short8*)&Ks[r1][c1] = kb;
            *(short8*)&Vt[r0][c0] = va;
            *(short8*)&Vt[r1][c1] = vb;
            __syncthreads();
        }
    }

    #pragma unroll
    for (int c = 0; c < 4; ++c) {
        #pragma unroll
        for (int i = 0; i < 4; ++i) {
            int qr = qbase + wave * 16 + g4 + i;
            float v = Oa[c][i] / La[i];
            AO[((size_t)(b * TT + qr) << 10) + h * 64 + c * 16 + lr] = f2bf(v);
        }
    }
}

// ---------------------------------------------------------------------------
extern "C" void kernel_launch(void* const* d_in, const int* in_sizes, int n_in,
                              void* d_out, int out_size, void* d_ws, size_t ws_size,
                              hipStream_t stream)
{
    char* ws = (char*)d_ws;
    const size_t XB  = (size_t)TM * TD * 2;   // 8 MiB bf16 x
    const size_t WB  = (size_t)TD * TD * 2;   // 2 MiB bf16 weight
    const size_t BUF = (size_t)TM * TD * 2;   // 8 MiB activation

    short* xb  = (short*)(ws + 256);
    short* Wqb = (short*)(ws + 256 + XB);
    short* Wkb = (short*)(ws + 256 + XB + WB);
    short* Wvb = (short*)(ws + 256 + XB + 2 * WB);
    short* Wob = (short*)(ws + 256 + XB + 3 * WB);
    char*  act = ws + 256 + XB + 4 * WB;
    short* Qb = (short*)(act);
    short* Kb = (short*)(act + BUF);
    short* Vb = (short*)(act + 2 * BUF);   // V^T [B,H,64,T]
    short* Ab = (short*)(act + 3 * BUF);
    char*  part = act + 4 * BUF;
    short* Opart = (short*)part;                               // 16 MiB
    float* lbuf  = (float*)(part + (size_t)16 * 1024 * 1024);  // 512 KiB

    const size_t need = 256 + XB + 4 * WB + 4 * BUF +
                        (size_t)16 * 1024 * 1024 + 524288;
    const bool splitS = (ws_size >= need);   // constant across calls: graph-safe

    dim3 blk(256);
    convert_all_kernel<<<dim3(512 + 4 * 128), blk, 0, stream>>>(
        d_in[0], d_in[1], d_in[2], d_in[3], d_in[4], xb, Wqb, Wkb, Wvb, Wob);
    qkv_gemm_kernel<<<dim3(TM / 128, TD / 128, 3), blk, 0, stream>>>(xb, Wqb, Wkb, Wvb, Qb, Kb, Vb);
    if (splitS) {
        attn_split_kernel<<<dim3(32, 32), blk, 0, stream>>>(Qb, Kb, Vb, Opart, lbuf);
        attn_merge_kernel<<<dim3(32, 16), blk, 0, stream>>>(Opart, lbuf, Ab);
    } else {
        attn_kernel<<<dim3(32, 32), blk, 0, stream>>>(Qb, Kb, Vb, Ab);
    }
    out_gemm_kernel<<<dim3(TM / 64, TD / 128), blk, 0, stream>>>(
        Ab, Wob, d_out, (const unsigned short*)d_in[0]);
}